// Round 1
// baseline (624.360 us; speedup 1.0000x reference)
//
#include <hip/hip_runtime.h>
#include <stdint.h>

#define SEQ    4096
#define HID    2048
#define NQKV   6144
#define NH     16
#define HD     128
#define SCALE  0.08838834764831845f

typedef unsigned short u16;
typedef __attribute__((ext_vector_type(8))) short bf16x8;
typedef __attribute__((ext_vector_type(4))) float f32x4;

__device__ __forceinline__ u16 f2bf(float f) {
  union { float f; unsigned u; } v; v.f = f;
  unsigned r = v.u + 0x7FFFu + ((v.u >> 16) & 1u);
  return (u16)(r >> 16);
}

__device__ __forceinline__ void async16(const u16* g, u16* l) {
  __builtin_amdgcn_global_load_lds(
      (const __attribute__((address_space(1))) unsigned int*)g,
      (__attribute__((address_space(3))) unsigned int*)l, 16, 0, 0);
}

// ---------------- fp32 -> bf16 convert (X) ----------------
__global__ __launch_bounds__(256) void cvt_f32_bf16(const float* __restrict__ in,
                                                    u16* __restrict__ out, int n4) {
  int i = blockIdx.x * 256 + threadIdx.x;
  if (i >= n4) return;
  float4 v = ((const float4*)in)[i];
  ushort4 o;
  o.x = f2bf(v.x); o.y = f2bf(v.y); o.z = f2bf(v.z); o.w = f2bf(v.w);
  ((ushort4*)out)[i] = o;
}

// ---------------- weight transpose: W[K=2048][N=2048] fp32 -> Wt[n][k] bf16 ----------------
__global__ __launch_bounds__(256) void transpose_w(const float* __restrict__ W,
                                                   u16* __restrict__ Wt) {
  __shared__ __align__(16) u16 Ts[64 * 72];
  const int n0 = blockIdx.x * 64;
  const int k0 = blockIdx.y * 64;
  const int t = threadIdx.x;
#pragma unroll
  for (int p = 0; p < 4; ++p) {
    int f = (t + p * 256) * 4;
    int r = f >> 6, c = f & 63;            // r=k_local, c=n_local
    float4 v = *(const float4*)&W[(size_t)(k0 + r) * 2048 + n0 + c];
    ushort4 o; o.x = f2bf(v.x); o.y = f2bf(v.y); o.z = f2bf(v.z); o.w = f2bf(v.w);
    *(ushort4*)&Ts[r * 72 + c] = o;
  }
  __syncthreads();
#pragma unroll
  for (int p = 0; p < 4; ++p) {
    int g = (t + p * 256) * 4;
    int r = g >> 6, c = g & 63;            // r=n_local, c=k_local
    ushort4 o;
    o.x = Ts[(c + 0) * 72 + r];
    o.y = Ts[(c + 1) * 72 + r];
    o.z = Ts[(c + 2) * 72 + r];
    o.w = Ts[(c + 3) * 72 + r];
    *(ushort4*)&Wt[(size_t)(n0 + r) * 2048 + k0 + c] = o;
  }
}

// ---------------- V transpose: QKV[s][4096 + h*128 + d] -> VT[h][d][s] (bf16) ----------------
__global__ __launch_bounds__(256) void transpose_v(const u16* __restrict__ qkv,
                                                   u16* __restrict__ vt) {
  __shared__ __align__(16) u16 Ts[64 * 72];
  const int s0 = blockIdx.x * 64;
  const int d0 = blockIdx.y * 64;
  const int h = blockIdx.z;
  const int t = threadIdx.x;
#pragma unroll
  for (int p = 0; p < 2; ++p) {
    int f = (t + p * 256) * 8;
    int r = f >> 6, c = f & 63;            // r=s_local, c=d_local
    uint4 v = *(const uint4*)&qkv[(size_t)(s0 + r) * NQKV + 4096 + h * HD + d0 + c];
    *(uint4*)&Ts[r * 72 + c] = v;
  }
  __syncthreads();
#pragma unroll
  for (int p = 0; p < 2; ++p) {
    int g = (t + p * 256) * 8;
    int r = g >> 6, c = g & 63;            // r=d_local, c=s_local
    u16 tmp[8];
#pragma unroll
    for (int j = 0; j < 8; ++j) tmp[j] = Ts[(c + j) * 72 + r];
    *(uint4*)&vt[(size_t)h * (HD * SEQ) + (size_t)(d0 + r) * SEQ + s0 + c] = *(uint4*)tmp;
  }
}

// ---------------- GEMM: C[m][n] = sum_k A[m][k] * Bt[n][k]  (bf16 in, fp32 acc) ----------------
template <typename OutT>
__global__ __launch_bounds__(256) void gemm_bt(const u16* __restrict__ A,
                                               const u16* __restrict__ B,
                                               OutT* __restrict__ C,
                                               int K, int ldc) {
  __shared__ __align__(16) u16 As[128 * 32];
  __shared__ __align__(16) u16 Bs[128 * 32];
  const int m0 = blockIdx.y * 128;
  const int n0 = blockIdx.x * 128;
  const int tid = threadIdx.x;
  const int wid = tid >> 6;
  const int lane = tid & 63;
  const int wm = wid & 1, wn = wid >> 1;
  const int l15 = lane & 15, g4 = lane >> 4;

  const int srow = wid * 32 + (lane >> 2);
  const int scol = (lane & 3) * 8;

  f32x4 acc[4][4] = {};

  const u16* pa0 = &A[(size_t)(m0 + srow) * K + scol];
  const u16* pa1 = &A[(size_t)(m0 + srow + 16) * K + scol];
  const u16* pb0 = &B[(size_t)(n0 + srow) * K + scol];
  const u16* pb1 = &B[(size_t)(n0 + srow + 16) * K + scol];
  u16* la0 = &As[(wid * 32) * 32];
  u16* la1 = &As[(wid * 32 + 16) * 32];
  u16* lb0 = &Bs[(wid * 32) * 32];
  u16* lb1 = &Bs[(wid * 32 + 16) * 32];

  for (int kt = 0; kt < K; kt += 32) {
    __syncthreads();
    async16(pa0 + kt, la0);
    async16(pa1 + kt, la1);
    async16(pb0 + kt, lb0);
    async16(pb1 + kt, lb1);
    __syncthreads();
    bf16x8 af[4], bfr[4];
#pragma unroll
    for (int i = 0; i < 4; ++i)
      af[i] = *(const bf16x8*)&As[(wm * 64 + i * 16 + l15) * 32 + g4 * 8];
#pragma unroll
    for (int i = 0; i < 4; ++i)
      bfr[i] = *(const bf16x8*)&Bs[(wn * 64 + i * 16 + l15) * 32 + g4 * 8];
#pragma unroll
    for (int mi = 0; mi < 4; ++mi)
#pragma unroll
      for (int ni = 0; ni < 4; ++ni)
        acc[mi][ni] = __builtin_amdgcn_mfma_f32_16x16x32_bf16(af[mi], bfr[ni], acc[mi][ni], 0, 0, 0);
  }
#pragma unroll
  for (int mi = 0; mi < 4; ++mi)
#pragma unroll
    for (int ni = 0; ni < 4; ++ni) {
      const int n = n0 + wn * 64 + ni * 16 + l15;
#pragma unroll
      for (int r = 0; r < 4; ++r) {
        const int m = m0 + wm * 64 + mi * 16 + g4 * 4 + r;
        float v = acc[mi][ni][r];
        if constexpr (sizeof(OutT) == 2) {
          C[(size_t)m * ldc + n] = (OutT)f2bf(v);
        } else {
          C[(size_t)m * ldc + n] = v;
        }
      }
    }
}

// ---------------- flash attention: 64-q x 64-kv tiles, sliding window + global ----------------
__global__ __launch_bounds__(256) void attn_kernel(const u16* __restrict__ qkv,
                                                   const u16* __restrict__ vt,
                                                   u16* __restrict__ out) {
  __shared__ __align__(16) u16 Qs[64 * 136];   // [q][d], stride 136 (pad 8) for bank spread
  __shared__ __align__(16) u16 Ks[64 * 136];   // [kv][d]
  __shared__ __align__(16) u16 VTs[128 * 72];  // [d][kv], stride 72
  __shared__ __align__(16) u16 Ps[64 * 72];    // [q][kv], stride 72
  const int q0 = blockIdx.x * 64;
  const int h = blockIdx.y;
  const int tid = threadIdx.x;
  const int w = tid >> 6;
  const int lane = tid & 63;
  const int l15 = lane & 15, g4 = lane >> 4;

  // stage Q tile (once)
#pragma unroll
  for (int p = 0; p < 4; ++p) {
    int f = (tid + p * 256) * 8;
    int r = f >> 7, c = f & 127;
    uint4 v = *(const uint4*)&qkv[(size_t)(q0 + r) * NQKV + h * HD + c];
    *(uint4*)&Qs[r * 136 + c] = v;
  }

  float m_run = -1e30f, l_run = 0.f;
  f32x4 o[8] = {};

  int lo_blk, hi_blk;
  if (q0 == 0) { lo_blk = 0; hi_blk = 63; }
  else {
    int lo = q0 - 255;
    lo_blk = (lo < 0) ? 0 : (lo >> 6);
    hi_blk = (q0 + 318) >> 6;
    if (hi_blk > 63) hi_blk = 63;
  }
  const int extra = (lo_blk > 0) ? 1 : 0;     // kb=0 pre-pass for global cols
  const int nsteps = hi_blk - lo_blk + 1 + extra;

  for (int step = 0; step < nsteps; ++step) {
    const int kb = (extra && step == 0) ? 0 : (lo_blk + step - extra);
    const int kv0 = kb * 64;
    __syncthreads();   // prior iteration's Ks/VTs reads done
    // stage K tile [64 kv][128 d]
#pragma unroll
    for (int p = 0; p < 4; ++p) {
      int f = (tid + p * 256) * 8;
      int r = f >> 7, c = f & 127;
      uint4 v = *(const uint4*)&qkv[(size_t)(kv0 + r) * NQKV + 2048 + h * HD + c];
      *(uint4*)&Ks[r * 136 + c] = v;
    }
    // stage V^T tile [128 d][64 kv]
#pragma unroll
    for (int p = 0; p < 4; ++p) {
      int f = (tid + p * 256) * 8;
      int r = f >> 6, c = f & 63;
      uint4 v = *(const uint4*)&vt[(size_t)h * (HD * SEQ) + (size_t)r * SEQ + kv0 + c];
      *(uint4*)&VTs[r * 72 + c] = v;
    }
    __syncthreads();

    // S^T = K @ Q^T : wave w owns q columns [w*16, w*16+16)
    f32x4 st[4] = {};
#pragma unroll
    for (int kk = 0; kk < 4; ++kk) {
      bf16x8 bq = *(const bf16x8*)&Qs[(w * 16 + l15) * 136 + kk * 32 + g4 * 8];
#pragma unroll
      for (int t4 = 0; t4 < 4; ++t4) {
        bf16x8 ak = *(const bf16x8*)&Ks[(t4 * 16 + l15) * 136 + kk * 32 + g4 * 8];
        st[t4] = __builtin_amdgcn_mfma_f32_16x16x32_bf16(ak, bq, st[t4], 0, 0, 0);
      }
    }

    // online softmax per q column (q = column index = lane&15 within wave)
    const int q = q0 + w * 16 + l15;
    float pv[4][4];
    float cmax = -1e30f;
#pragma unroll
    for (int t4 = 0; t4 < 4; ++t4)
#pragma unroll
      for (int r = 0; r < 4; ++r) {
        int kv = kv0 + t4 * 16 + g4 * 4 + r;
        int dq = q - kv; if (dq < 0) dq = -dq;
        bool ok = (dq < 256) || (q < 16) || (kv < 16);
        float s = ok ? st[t4][r] * SCALE : -1e30f;
        pv[t4][r] = s;
        cmax = fmaxf(cmax, s);
      }
    cmax = fmaxf(cmax, __shfl_xor(cmax, 16, 64));
    cmax = fmaxf(cmax, __shfl_xor(cmax, 32, 64));
    float mnew = fmaxf(m_run, cmax);
    float csum = 0.f;
#pragma unroll
    for (int t4 = 0; t4 < 4; ++t4)
#pragma unroll
      for (int r = 0; r < 4; ++r) {
        float p = __expf(pv[t4][r] - mnew);
        pv[t4][r] = p;
        csum += p;
      }
    csum += __shfl_xor(csum, 16, 64);
    csum += __shfl_xor(csum, 32, 64);
    float alpha = __expf(m_run - mnew);
    m_run = mnew;
    l_run = l_run * alpha + csum;

    // write P (bf16) into [q][kv] tile; 4 consecutive kv (regs) pack to 8B
#pragma unroll
    for (int t4 = 0; t4 < 4; ++t4) {
      u16 pk[4];
#pragma unroll
      for (int r = 0; r < 4; ++r) pk[r] = f2bf(pv[t4][r]);
      *(uint2*)&Ps[(w * 16 + l15) * 72 + t4 * 16 + g4 * 4] = *(uint2*)pk;
    }

    // rescale O accumulator (O rows are q = g4*4 + r → fetch that column's alpha)
    float al[4];
#pragma unroll
    for (int r = 0; r < 4; ++r) al[r] = __shfl(alpha, g4 * 4 + r, 64);
#pragma unroll
    for (int nt = 0; nt < 8; ++nt)
#pragma unroll
      for (int r = 0; r < 4; ++r) o[nt][r] *= al[r];
    __syncthreads();   // Ps visible (also keeps waves in step)

    // O += P @ V : A = Ps rows of this wave, B = VTs
#pragma unroll
    for (int ks = 0; ks < 2; ++ks) {
      bf16x8 ap = *(const bf16x8*)&Ps[(w * 16 + l15) * 72 + ks * 32 + g4 * 8];
#pragma unroll
      for (int nt = 0; nt < 8; ++nt) {
        bf16x8 bv = *(const bf16x8*)&VTs[(nt * 16 + l15) * 72 + ks * 32 + g4 * 8];
        o[nt] = __builtin_amdgcn_mfma_f32_16x16x32_bf16(ap, bv, o[nt], 0, 0, 0);
      }
    }
  }

  // finalize: divide by l (per q row), write bf16
  float lr[4];
#pragma unroll
  for (int r = 0; r < 4; ++r) lr[r] = 1.f / __shfl(l_run, g4 * 4 + r, 64);
#pragma unroll
  for (int nt = 0; nt < 8; ++nt)
#pragma unroll
    for (int r = 0; r < 4; ++r) {
      const int m = q0 + w * 16 + g4 * 4 + r;
      const int n = h * HD + nt * 16 + l15;
      out[(size_t)m * HID + n] = f2bf(o[nt][r] * lr[r]);
    }
}

extern "C" void kernel_launch(void* const* d_in, const int* in_sizes, int n_in,
                              void* d_out, int out_size, void* d_ws, size_t ws_size,
                              hipStream_t stream) {
  const float* X  = (const float*)d_in[0];
  const float* Wq = (const float*)d_in[1];
  const float* Wk = (const float*)d_in[2];
  const float* Wv = (const float*)d_in[3];
  const float* Wo = (const float*)d_in[4];
  float* out = (float*)d_out;

  // workspace layout (96 MiB total, with lifetime-based aliasing):
  //  [0,16M):  Xbf      (dead after QKV GEMM)  -> reused as VT
  //  [16M,40M): Wcat_t  (dead after QKV GEMM)  -> first 16M reused as AttnOut
  //  [40M,88M): QKV bf16 [4096][6144]
  //  [88M,96M): Wo^T bf16
  char* ws = (char*)d_ws;
  u16* Xbf   = (u16*)(ws);
  u16* Wcat  = (u16*)(ws + (size_t)(16 << 20));
  u16* VT    = (u16*)(ws);                          // alias Xbf
  u16* AttnO = (u16*)(ws + (size_t)(16 << 20));     // alias Wcat
  u16* QKV   = (u16*)(ws + (size_t)(40 << 20));
  u16* Wot   = (u16*)(ws + (size_t)(88 << 20));

  // 1) X -> bf16
  cvt_f32_bf16<<<dim3(8192), dim3(256), 0, stream>>>(X, Xbf, (SEQ * HID) / 4);
  // 2) weight transposes (fp32 [k][n] -> bf16 [n][k])
  dim3 tw(32, 32);
  transpose_w<<<tw, 256, 0, stream>>>(Wq, Wcat);
  transpose_w<<<tw, 256, 0, stream>>>(Wk, Wcat + (size_t)2048 * 2048);
  transpose_w<<<tw, 256, 0, stream>>>(Wv, Wcat + (size_t)2 * 2048 * 2048);
  transpose_w<<<tw, 256, 0, stream>>>(Wo, Wot);
  // 3) fused QKV GEMM: [4096][2048] x [6144][2048]^T -> [4096][6144] bf16
  gemm_bt<u16><<<dim3(48, 32), 256, 0, stream>>>(Xbf, Wcat, QKV, HID, NQKV);
  // 4) V -> VT[h][d][s]
  transpose_v<<<dim3(64, 2, 16), 256, 0, stream>>>(QKV, VT);
  // 5) attention
  attn_kernel<<<dim3(64, 16), 256, 0, stream>>>(QKV, VT, AttnO);
  // 6) output projection: [4096][2048] x [2048][2048]^T -> fp32 out
  gemm_bt<float><<<dim3(16, 32), 256, 0, stream>>>(AttnO, Wot, out, HID, HID);
}

// Round 2
// 452.786 us; speedup vs baseline: 1.3789x; 1.3789x over previous
//
#include <hip/hip_runtime.h>
#include <stdint.h>

#define SEQ    4096
#define HID    2048
#define NQKV   6144
#define NH     16
#define HD     128
#define SCALE  0.08838834764831845f
#define GQC    32   // split-KV chunks for global-query kernel (128 kv each)

typedef unsigned short u16;
typedef __attribute__((ext_vector_type(8))) short bf16x8;
typedef __attribute__((ext_vector_type(4))) float f32x4;

__device__ __forceinline__ u16 f2bf(float f) {
  union { float f; unsigned u; } v; v.f = f;
  unsigned r = v.u + 0x7FFFu + ((v.u >> 16) & 1u);
  return (u16)(r >> 16);
}

__device__ __forceinline__ float bf2f(u16 b) {
  union { unsigned u; float f; } c; c.u = ((unsigned)b) << 16; return c.f;
}

__device__ __forceinline__ void async16(const u16* g, u16* l) {
  __builtin_amdgcn_global_load_lds(
      (const __attribute__((address_space(1))) unsigned int*)g,
      (__attribute__((address_space(3))) unsigned int*)l, 16, 0, 0);
}

// ---------------- fp32 -> bf16 convert (X) ----------------
__global__ __launch_bounds__(256) void cvt_f32_bf16(const float* __restrict__ in,
                                                    u16* __restrict__ out, int n4) {
  int i = blockIdx.x * 256 + threadIdx.x;
  if (i >= n4) return;
  float4 v = ((const float4*)in)[i];
  ushort4 o;
  o.x = f2bf(v.x); o.y = f2bf(v.y); o.z = f2bf(v.z); o.w = f2bf(v.w);
  ((ushort4*)out)[i] = o;
}

// ---------------- weight transpose: W[K=2048][N=2048] fp32 -> Wt[n][k] bf16 ----------------
__global__ __launch_bounds__(256) void transpose_w(const float* __restrict__ W,
                                                   u16* __restrict__ Wt) {
  __shared__ __align__(16) u16 Ts[64 * 72];
  const int n0 = blockIdx.x * 64;
  const int k0 = blockIdx.y * 64;
  const int t = threadIdx.x;
#pragma unroll
  for (int p = 0; p < 4; ++p) {
    int f = (t + p * 256) * 4;
    int r = f >> 6, c = f & 63;            // r=k_local, c=n_local
    float4 v = *(const float4*)&W[(size_t)(k0 + r) * 2048 + n0 + c];
    ushort4 o; o.x = f2bf(v.x); o.y = f2bf(v.y); o.z = f2bf(v.z); o.w = f2bf(v.w);
    *(ushort4*)&Ts[r * 72 + c] = o;
  }
  __syncthreads();
#pragma unroll
  for (int p = 0; p < 4; ++p) {
    int g = (t + p * 256) * 4;
    int r = g >> 6, c = g & 63;            // r=n_local, c=k_local
    ushort4 o;
    o.x = Ts[(c + 0) * 72 + r];
    o.y = Ts[(c + 1) * 72 + r];
    o.z = Ts[(c + 2) * 72 + r];
    o.w = Ts[(c + 3) * 72 + r];
    *(ushort4*)&Wt[(size_t)(n0 + r) * 2048 + k0 + c] = o;
  }
}

// ---------------- V transpose: QKV[s][4096 + h*128 + d] -> VT[h][d][s] (bf16) ----------------
__global__ __launch_bounds__(256) void transpose_v(const u16* __restrict__ qkv,
                                                   u16* __restrict__ vt) {
  __shared__ __align__(16) u16 Ts[64 * 72];
  const int s0 = blockIdx.x * 64;
  const int d0 = blockIdx.y * 64;
  const int h = blockIdx.z;
  const int t = threadIdx.x;
#pragma unroll
  for (int p = 0; p < 2; ++p) {
    int f = (t + p * 256) * 8;
    int r = f >> 6, c = f & 63;            // r=s_local, c=d_local
    uint4 v = *(const uint4*)&qkv[(size_t)(s0 + r) * NQKV + 4096 + h * HD + d0 + c];
    *(uint4*)&Ts[r * 72 + c] = v;
  }
  __syncthreads();
#pragma unroll
  for (int p = 0; p < 2; ++p) {
    int g = (t + p * 256) * 8;
    int r = g >> 6, c = g & 63;            // r=d_local, c=s_local
    u16 tmp[8];
#pragma unroll
    for (int j = 0; j < 8; ++j) tmp[j] = Ts[(c + j) * 72 + r];
    *(uint4*)&vt[(size_t)h * (HD * SEQ) + (size_t)(d0 + r) * SEQ + s0 + c] = *(uint4*)tmp;
  }
}

// ---------------- GEMM: C[m][n] = sum_k A[m][k] * Bt[n][k]  (bf16 in, fp32 acc) ----------------
template <typename OutT>
__global__ __launch_bounds__(256) void gemm_bt(const u16* __restrict__ A,
                                               const u16* __restrict__ B,
                                               OutT* __restrict__ C,
                                               int K, int ldc) {
  __shared__ __align__(16) u16 As[128 * 32];
  __shared__ __align__(16) u16 Bs[128 * 32];
  const int m0 = blockIdx.y * 128;
  const int n0 = blockIdx.x * 128;
  const int tid = threadIdx.x;
  const int wid = tid >> 6;
  const int lane = tid & 63;
  const int wm = wid & 1, wn = wid >> 1;
  const int l15 = lane & 15, g4 = lane >> 4;

  const int srow = wid * 32 + (lane >> 2);
  const int scol = (lane & 3) * 8;

  f32x4 acc[4][4] = {};

  const u16* pa0 = &A[(size_t)(m0 + srow) * K + scol];
  const u16* pa1 = &A[(size_t)(m0 + srow + 16) * K + scol];
  const u16* pb0 = &B[(size_t)(n0 + srow) * K + scol];
  const u16* pb1 = &B[(size_t)(n0 + srow + 16) * K + scol];
  u16* la0 = &As[(wid * 32) * 32];
  u16* la1 = &As[(wid * 32 + 16) * 32];
  u16* lb0 = &Bs[(wid * 32) * 32];
  u16* lb1 = &Bs[(wid * 32 + 16) * 32];

  for (int kt = 0; kt < K; kt += 32) {
    __syncthreads();
    async16(pa0 + kt, la0);
    async16(pa1 + kt, la1);
    async16(pb0 + kt, lb0);
    async16(pb1 + kt, lb1);
    __syncthreads();
    bf16x8 af[4], bfr[4];
#pragma unroll
    for (int i = 0; i < 4; ++i)
      af[i] = *(const bf16x8*)&As[(wm * 64 + i * 16 + l15) * 32 + g4 * 8];
#pragma unroll
    for (int i = 0; i < 4; ++i)
      bfr[i] = *(const bf16x8*)&Bs[(wn * 64 + i * 16 + l15) * 32 + g4 * 8];
#pragma unroll
    for (int mi = 0; mi < 4; ++mi)
#pragma unroll
      for (int ni = 0; ni < 4; ++ni)
        acc[mi][ni] = __builtin_amdgcn_mfma_f32_16x16x32_bf16(af[mi], bfr[ni], acc[mi][ni], 0, 0, 0);
  }
#pragma unroll
  for (int mi = 0; mi < 4; ++mi)
#pragma unroll
    for (int ni = 0; ni < 4; ++ni) {
      const int n = n0 + wn * 64 + ni * 16 + l15;
#pragma unroll
      for (int r = 0; r < 4; ++r) {
        const int m = m0 + wm * 64 + mi * 16 + g4 * 4 + r;
        float v = acc[mi][ni][r];
        if constexpr (sizeof(OutT) == 2) {
          C[(size_t)m * ldc + n] = (OutT)f2bf(v);
        } else {
          C[(size_t)m * ldc + n] = v;
        }
      }
    }
}

// ---------------- flash attention (local window + global-kv only) ----------------
// Global QUERIES (q<16) are handled by attn_global/attn_gred; this kernel does
// not write rows 0-15, so every block runs the uniform ~10-step schedule.
__global__ __launch_bounds__(256) void attn_kernel(const u16* __restrict__ qkv,
                                                   const u16* __restrict__ vt,
                                                   u16* __restrict__ out) {
  __shared__ __align__(16) u16 Qs[64 * 136];   // [q][d], stride 136 (pad 8)
  __shared__ __align__(16) u16 Ks[64 * 136];   // [kv][d]
  __shared__ __align__(16) u16 VTs[128 * 72];  // [d][kv], stride 72
  __shared__ __align__(16) u16 Ps[64 * 72];    // [q][kv], stride 72
  const int q0 = blockIdx.x * 64;
  const int h = blockIdx.y;
  const int tid = threadIdx.x;
  const int w = tid >> 6;
  const int lane = tid & 63;
  const int l15 = lane & 15, g4 = lane >> 4;

  // stage Q tile (once)
#pragma unroll
  for (int p = 0; p < 4; ++p) {
    int f = (tid + p * 256) * 8;
    int r = f >> 7, c = f & 127;
    uint4 v = *(const uint4*)&qkv[(size_t)(q0 + r) * NQKV + h * HD + c];
    *(uint4*)&Qs[r * 136 + c] = v;
  }

  float m_run = -1e30f, l_run = 0.f;
  f32x4 o[8] = {};

  int lo = q0 - 255;
  int lo_blk = (lo < 0) ? 0 : (lo >> 6);
  int hi_blk = (q0 + 318) >> 6;
  if (hi_blk > 63) hi_blk = 63;
  const int extra = (lo_blk > 0) ? 1 : 0;     // kb=0 pre-pass for global kv cols
  const int nsteps = hi_blk - lo_blk + 1 + extra;

  for (int step = 0; step < nsteps; ++step) {
    const int kb = (extra && step == 0) ? 0 : (lo_blk + step - extra);
    const int kv0 = kb * 64;
    __syncthreads();   // prior iteration's Ks/VTs reads done
    // stage K tile [64 kv][128 d]
#pragma unroll
    for (int p = 0; p < 4; ++p) {
      int f = (tid + p * 256) * 8;
      int r = f >> 7, c = f & 127;
      uint4 v = *(const uint4*)&qkv[(size_t)(kv0 + r) * NQKV + 2048 + h * HD + c];
      *(uint4*)&Ks[r * 136 + c] = v;
    }
    // stage V^T tile [128 d][64 kv]
#pragma unroll
    for (int p = 0; p < 4; ++p) {
      int f = (tid + p * 256) * 8;
      int r = f >> 6, c = f & 63;
      uint4 v = *(const uint4*)&vt[(size_t)h * (HD * SEQ) + (size_t)r * SEQ + kv0 + c];
      *(uint4*)&VTs[r * 72 + c] = v;
    }
    __syncthreads();

    // S^T = K @ Q^T : wave w owns q columns [w*16, w*16+16)
    f32x4 st[4] = {};
#pragma unroll
    for (int kk = 0; kk < 4; ++kk) {
      bf16x8 bq = *(const bf16x8*)&Qs[(w * 16 + l15) * 136 + kk * 32 + g4 * 8];
#pragma unroll
      for (int t4 = 0; t4 < 4; ++t4) {
        bf16x8 ak = *(const bf16x8*)&Ks[(t4 * 16 + l15) * 136 + kk * 32 + g4 * 8];
        st[t4] = __builtin_amdgcn_mfma_f32_16x16x32_bf16(ak, bq, st[t4], 0, 0, 0);
      }
    }

    // online softmax per q column (q = column index = lane&15 within wave)
    const int q = q0 + w * 16 + l15;
    float pv[4][4];
    float cmax = -1e30f;
#pragma unroll
    for (int t4 = 0; t4 < 4; ++t4)
#pragma unroll
      for (int r = 0; r < 4; ++r) {
        int kv = kv0 + t4 * 16 + g4 * 4 + r;
        int dq = q - kv; if (dq < 0) dq = -dq;
        bool ok = (dq < 256) || (kv < 16);
        float s = ok ? st[t4][r] * SCALE : -1e30f;
        pv[t4][r] = s;
        cmax = fmaxf(cmax, s);
      }
    cmax = fmaxf(cmax, __shfl_xor(cmax, 16, 64));
    cmax = fmaxf(cmax, __shfl_xor(cmax, 32, 64));
    float mnew = fmaxf(m_run, cmax);
    float csum = 0.f;
#pragma unroll
    for (int t4 = 0; t4 < 4; ++t4)
#pragma unroll
      for (int r = 0; r < 4; ++r) {
        float p = __expf(pv[t4][r] - mnew);
        pv[t4][r] = p;
        csum += p;
      }
    csum += __shfl_xor(csum, 16, 64);
    csum += __shfl_xor(csum, 32, 64);
    float alpha = __expf(m_run - mnew);
    m_run = mnew;
    l_run = l_run * alpha + csum;

    // write P (bf16) into [q][kv] tile; 4 consecutive kv (regs) pack to 8B
#pragma unroll
    for (int t4 = 0; t4 < 4; ++t4) {
      u16 pk[4];
#pragma unroll
      for (int r = 0; r < 4; ++r) pk[r] = f2bf(pv[t4][r]);
      *(uint2*)&Ps[(w * 16 + l15) * 72 + t4 * 16 + g4 * 4] = *(uint2*)pk;
    }

    // rescale O accumulator (O rows are q = g4*4 + r → fetch that column's alpha)
    float al[4];
#pragma unroll
    for (int r = 0; r < 4; ++r) al[r] = __shfl(alpha, g4 * 4 + r, 64);
#pragma unroll
    for (int nt = 0; nt < 8; ++nt)
#pragma unroll
      for (int r = 0; r < 4; ++r) o[nt][r] *= al[r];
    __syncthreads();   // Ps visible (also keeps waves in step)

    // O += P @ V : A = Ps rows of this wave, B = VTs
#pragma unroll
    for (int ks = 0; ks < 2; ++ks) {
      bf16x8 ap = *(const bf16x8*)&Ps[(w * 16 + l15) * 72 + ks * 32 + g4 * 8];
#pragma unroll
      for (int nt = 0; nt < 8; ++nt) {
        bf16x8 bv = *(const bf16x8*)&VTs[(nt * 16 + l15) * 72 + ks * 32 + g4 * 8];
        o[nt] = __builtin_amdgcn_mfma_f32_16x16x32_bf16(ap, bv, o[nt], 0, 0, 0);
      }
    }
  }

  // finalize: divide by l (per q row), write bf16; skip global-query rows (<16)
  float lr[4];
#pragma unroll
  for (int r = 0; r < 4; ++r) lr[r] = 1.f / __shfl(l_run, g4 * 4 + r, 64);
#pragma unroll
  for (int nt = 0; nt < 8; ++nt)
#pragma unroll
    for (int r = 0; r < 4; ++r) {
      const int m = q0 + w * 16 + g4 * 4 + r;
      if (m < 16) continue;
      const int n = h * HD + nt * 16 + l15;
      out[(size_t)m * HID + n] = f2bf(o[nt][r] * lr[r]);
    }
}

// ---------------- global queries (q<16): split-KV VALU flash, partials ----------------
// grid (GQC, NH), block 256. thread t: q = t>>4, dg = t&15 (owns d slice dg*8..+8)
__global__ __launch_bounds__(256) void attn_global(const u16* __restrict__ qkv,
                                                   float* __restrict__ Opart,
                                                   float* __restrict__ MLpart) {
  __shared__ __align__(16) u16 Ks[64 * 136];
  __shared__ __align__(16) u16 Vs[64 * 136];
  const int chunk = blockIdx.x, h = blockIdx.y;
  const int t = threadIdx.x;
  const int q = t >> 4, dg = t & 15;

  float qr[8];
  {
    bf16x8 v = *(const bf16x8*)&qkv[(size_t)q * NQKV + h * HD + dg * 8];
#pragma unroll
    for (int j = 0; j < 8; ++j) qr[j] = bf2f((u16)v[j]);
  }
  float m_run = -1e30f, l_run = 0.f, o[8] = {};
  const int kvbase = chunk * (SEQ / GQC);

  for (int st = 0; st < (SEQ / GQC) / 64; ++st) {
    const int kv0 = kvbase + st * 64;
    __syncthreads();
#pragma unroll
    for (int p = 0; p < 4; ++p) {
      int f = (t + p * 256) * 8;
      int r = f >> 7, c = f & 127;
      *(uint4*)&Ks[r * 136 + c] = *(const uint4*)&qkv[(size_t)(kv0 + r) * NQKV + 2048 + h * HD + c];
      *(uint4*)&Vs[r * 136 + c] = *(const uint4*)&qkv[(size_t)(kv0 + r) * NQKV + 4096 + h * HD + c];
    }
    __syncthreads();
    for (int kv = 0; kv < 64; ++kv) {
      bf16x8 kr = *(const bf16x8*)&Ks[kv * 136 + dg * 8];
      float s = 0.f;
#pragma unroll
      for (int j = 0; j < 8; ++j) s += qr[j] * bf2f((u16)kr[j]);
      s += __shfl_xor(s, 1, 64); s += __shfl_xor(s, 2, 64);
      s += __shfl_xor(s, 4, 64); s += __shfl_xor(s, 8, 64);
      s *= SCALE;
      float mnew = fmaxf(m_run, s);
      float alpha = __expf(m_run - mnew);
      float p = __expf(s - mnew);
      m_run = mnew;
      l_run = l_run * alpha + p;
      bf16x8 vr = *(const bf16x8*)&Vs[kv * 136 + dg * 8];
#pragma unroll
      for (int j = 0; j < 8; ++j) o[j] = o[j] * alpha + p * bf2f((u16)vr[j]);
    }
  }
  float* op = &Opart[(((size_t)h * GQC + chunk) * 16 + q) * HD + dg * 8];
#pragma unroll
  for (int j = 0; j < 8; ++j) op[j] = o[j];
  if (dg == 0) {
    float* ml = &MLpart[(((size_t)h * GQC + chunk) * 16 + q) * 2];
    ml[0] = m_run; ml[1] = l_run;
  }
}

// ---------------- combine split-KV partials, write rows 0-15 of AttnO ----------------
__global__ __launch_bounds__(256) void attn_gred(const float* __restrict__ Opart,
                                                 const float* __restrict__ MLpart,
                                                 u16* __restrict__ out) {
  const int h = blockIdx.x;
  const int t = threadIdx.x;
  const int q = t >> 4, dg = t & 15;
  float M = -1e30f;
  for (int c = 0; c < GQC; ++c)
    M = fmaxf(M, MLpart[(((size_t)h * GQC + c) * 16 + q) * 2]);
  float L = 0.f, o[8] = {};
  for (int c = 0; c < GQC; ++c) {
    const float* ml = &MLpart[(((size_t)h * GQC + c) * 16 + q) * 2];
    float e = __expf(ml[0] - M);
    L += e * ml[1];
    const float* op = &Opart[(((size_t)h * GQC + c) * 16 + q) * HD + dg * 8];
#pragma unroll
    for (int j = 0; j < 8; ++j) o[j] += e * op[j];
  }
  float inv = 1.f / L;
  u16 tmp[8];
#pragma unroll
  for (int j = 0; j < 8; ++j) tmp[j] = f2bf(o[j] * inv);
  *(uint4*)&out[(size_t)q * HID + h * HD + dg * 8] = *(uint4*)tmp;
}

extern "C" void kernel_launch(void* const* d_in, const int* in_sizes, int n_in,
                              void* d_out, int out_size, void* d_ws, size_t ws_size,
                              hipStream_t stream) {
  const float* X  = (const float*)d_in[0];
  const float* Wq = (const float*)d_in[1];
  const float* Wk = (const float*)d_in[2];
  const float* Wv = (const float*)d_in[3];
  const float* Wo = (const float*)d_in[4];
  float* out = (float*)d_out;

  // workspace layout (96 MiB total, lifetime-based aliasing):
  //  [0,16M):   Xbf   (dead after QKV GEMM) -> reused as VT
  //  [16M,40M): Wcat  (dead after QKV GEMM) -> [16M,32M) AttnO, [32M,36M) Opart,
  //                                            [36M,37M) MLpart
  //  [40M,88M): QKV bf16 [4096][6144]
  //  [88M,96M): Wo^T bf16
  char* ws = (char*)d_ws;
  u16* Xbf    = (u16*)(ws);
  u16* Wcat   = (u16*)(ws + (size_t)(16 << 20));
  u16* VT     = (u16*)(ws);                          // alias Xbf
  u16* AttnO  = (u16*)(ws + (size_t)(16 << 20));     // alias Wcat
  float* Opart  = (float*)(ws + (size_t)(32 << 20)); // alias Wcat tail (4 MB)
  float* MLpart = (float*)(ws + (size_t)(36 << 20)); // 64 KB
  u16* QKV    = (u16*)(ws + (size_t)(40 << 20));
  u16* Wot    = (u16*)(ws + (size_t)(88 << 20));

  // 1) X -> bf16
  cvt_f32_bf16<<<dim3(8192), dim3(256), 0, stream>>>(X, Xbf, (SEQ * HID) / 4);
  // 2) weight transposes (fp32 [k][n] -> bf16 [n][k])
  dim3 tw(32, 32);
  transpose_w<<<tw, 256, 0, stream>>>(Wq, Wcat);
  transpose_w<<<tw, 256, 0, stream>>>(Wk, Wcat + (size_t)2048 * 2048);
  transpose_w<<<tw, 256, 0, stream>>>(Wv, Wcat + (size_t)2 * 2048 * 2048);
  transpose_w<<<tw, 256, 0, stream>>>(Wo, Wot);
  // 3) fused QKV GEMM: [4096][2048] x [6144][2048]^T -> [4096][6144] bf16
  gemm_bt<u16><<<dim3(48, 32), 256, 0, stream>>>(Xbf, Wcat, QKV, HID, NQKV);
  // 4) global queries: split-KV partials (independent of VT)
  attn_global<<<dim3(GQC, NH), 256, 0, stream>>>(QKV, Opart, MLpart);
  // 5) V -> VT[h][d][s]
  transpose_v<<<dim3(64, 2, 16), 256, 0, stream>>>(QKV, VT);
  // 6) local attention (writes rows 16..4095)
  attn_kernel<<<dim3(64, 16), 256, 0, stream>>>(QKV, VT, AttnO);
  // 7) combine global-query partials (writes rows 0..15)
  attn_gred<<<dim3(NH), 256, 0, stream>>>(Opart, MLpart, AttnO);
  // 8) output projection: [4096][2048] x [2048][2048]^T -> fp32 out
  gemm_bt<float><<<dim3(16, 32), 256, 0, stream>>>(AttnO, Wot, out, HID, HID);
}

// Round 3
// 433.153 us; speedup vs baseline: 1.4414x; 1.0453x over previous
//
#include <hip/hip_runtime.h>
#include <stdint.h>

#define SEQ    4096
#define HID    2048
#define NQKV   6144
#define NH     16
#define HD     128
#define SCALE  0.08838834764831845f
#define GQC    32   // split-KV chunks for global-query kernel (128 kv each)

typedef unsigned short u16;
typedef __attribute__((ext_vector_type(8))) short bf16x8;
typedef __attribute__((ext_vector_type(4))) float f32x4;

__device__ __forceinline__ u16 f2bf(float f) {
  union { float f; unsigned u; } v; v.f = f;
  unsigned r = v.u + 0x7FFFu + ((v.u >> 16) & 1u);
  return (u16)(r >> 16);
}

__device__ __forceinline__ float bf2f(u16 b) {
  union { unsigned u; float f; } c; c.u = ((unsigned)b) << 16; return c.f;
}

__device__ __forceinline__ void async16(const u16* g, u16* l) {
  __builtin_amdgcn_global_load_lds(
      (const __attribute__((address_space(1))) unsigned int*)g,
      (__attribute__((address_space(3))) unsigned int*)l, 16, 0, 0);
}

// ---------------- fp32 -> bf16 convert (X) ----------------
__global__ __launch_bounds__(256) void cvt_f32_bf16(const float* __restrict__ in,
                                                    u16* __restrict__ out, int n4) {
  int i = blockIdx.x * 256 + threadIdx.x;
  if (i >= n4) return;
  float4 v = ((const float4*)in)[i];
  ushort4 o;
  o.x = f2bf(v.x); o.y = f2bf(v.y); o.z = f2bf(v.z); o.w = f2bf(v.w);
  ((ushort4*)out)[i] = o;
}

// ------ fused weight transposes: z selects {Wq,Wk,Wv}->Wcat, Wo->Wot ------
__global__ __launch_bounds__(256) void transpose_w4(const float* __restrict__ W0,
                                                    const float* __restrict__ W1,
                                                    const float* __restrict__ W2,
                                                    const float* __restrict__ W3,
                                                    u16* __restrict__ Wcat,
                                                    u16* __restrict__ Wot) {
  __shared__ __align__(16) u16 Ts[64 * 72];
  const int n0 = blockIdx.x * 64;
  const int k0 = blockIdx.y * 64;
  const int z = blockIdx.z;
  const float* W = (z == 0) ? W0 : (z == 1) ? W1 : (z == 2) ? W2 : W3;
  u16* Wt = (z < 3) ? (Wcat + (size_t)z * 2048 * 2048) : Wot;
  const int t = threadIdx.x;
#pragma unroll
  for (int p = 0; p < 4; ++p) {
    int f = (t + p * 256) * 4;
    int r = f >> 6, c = f & 63;            // r=k_local, c=n_local
    float4 v = *(const float4*)&W[(size_t)(k0 + r) * 2048 + n0 + c];
    ushort4 o; o.x = f2bf(v.x); o.y = f2bf(v.y); o.z = f2bf(v.z); o.w = f2bf(v.w);
    *(ushort4*)&Ts[r * 72 + c] = o;
  }
  __syncthreads();
#pragma unroll
  for (int p = 0; p < 4; ++p) {
    int g = (t + p * 256) * 4;
    int r = g >> 6, c = g & 63;            // r=n_local, c=k_local
    ushort4 o;
    o.x = Ts[(c + 0) * 72 + r];
    o.y = Ts[(c + 1) * 72 + r];
    o.z = Ts[(c + 2) * 72 + r];
    o.w = Ts[(c + 3) * 72 + r];
    *(ushort4*)&Wt[(size_t)(n0 + r) * 2048 + k0 + c] = o;
  }
}

// ---------------- V transpose: QKV[s][4096 + h*128 + d] -> VT[h][d][s] (bf16) ----------------
__global__ __launch_bounds__(256) void transpose_v(const u16* __restrict__ qkv,
                                                   u16* __restrict__ vt) {
  __shared__ __align__(16) u16 Ts[64 * 72];
  const int s0 = blockIdx.x * 64;
  const int d0 = blockIdx.y * 64;
  const int h = blockIdx.z;
  const int t = threadIdx.x;
#pragma unroll
  for (int p = 0; p < 2; ++p) {
    int f = (t + p * 256) * 8;
    int r = f >> 6, c = f & 63;            // r=s_local, c=d_local
    uint4 v = *(const uint4*)&qkv[(size_t)(s0 + r) * NQKV + 4096 + h * HD + d0 + c];
    *(uint4*)&Ts[r * 72 + c] = v;
  }
  __syncthreads();
#pragma unroll
  for (int p = 0; p < 2; ++p) {
    int g = (t + p * 256) * 8;
    int r = g >> 6, c = g & 63;            // r=d_local, c=s_local
    u16 tmp[8];
#pragma unroll
    for (int j = 0; j < 8; ++j) tmp[j] = Ts[(c + j) * 72 + r];
    *(uint4*)&vt[(size_t)h * (HD * SEQ) + (size_t)(d0 + r) * SEQ + s0 + c] = *(uint4*)tmp;
  }
}

// ---------------- GEMM: C[m][n] = sum_k A[m][k] * Bt[n][k]  (bf16 in, fp32 acc) ----------------
template <typename OutT>
__global__ __launch_bounds__(256) void gemm_bt(const u16* __restrict__ A,
                                               const u16* __restrict__ B,
                                               OutT* __restrict__ C,
                                               int K, int ldc) {
  __shared__ __align__(16) u16 As[128 * 32];
  __shared__ __align__(16) u16 Bs[128 * 32];
  const int m0 = blockIdx.y * 128;
  const int n0 = blockIdx.x * 128;
  const int tid = threadIdx.x;
  const int wid = tid >> 6;
  const int lane = tid & 63;
  const int wm = wid & 1, wn = wid >> 1;
  const int l15 = lane & 15, g4 = lane >> 4;

  const int srow = wid * 32 + (lane >> 2);
  const int scol = (lane & 3) * 8;

  f32x4 acc[4][4] = {};

  const u16* pa0 = &A[(size_t)(m0 + srow) * K + scol];
  const u16* pa1 = &A[(size_t)(m0 + srow + 16) * K + scol];
  const u16* pb0 = &B[(size_t)(n0 + srow) * K + scol];
  const u16* pb1 = &B[(size_t)(n0 + srow + 16) * K + scol];
  u16* la0 = &As[(wid * 32) * 32];
  u16* la1 = &As[(wid * 32 + 16) * 32];
  u16* lb0 = &Bs[(wid * 32) * 32];
  u16* lb1 = &Bs[(wid * 32 + 16) * 32];

  for (int kt = 0; kt < K; kt += 32) {
    __syncthreads();
    async16(pa0 + kt, la0);
    async16(pa1 + kt, la1);
    async16(pb0 + kt, lb0);
    async16(pb1 + kt, lb1);
    __syncthreads();
    bf16x8 af[4], bfr[4];
#pragma unroll
    for (int i = 0; i < 4; ++i)
      af[i] = *(const bf16x8*)&As[(wm * 64 + i * 16 + l15) * 32 + g4 * 8];
#pragma unroll
    for (int i = 0; i < 4; ++i)
      bfr[i] = *(const bf16x8*)&Bs[(wn * 64 + i * 16 + l15) * 32 + g4 * 8];
#pragma unroll
    for (int mi = 0; mi < 4; ++mi)
#pragma unroll
      for (int ni = 0; ni < 4; ++ni)
        acc[mi][ni] = __builtin_amdgcn_mfma_f32_16x16x32_bf16(af[mi], bfr[ni], acc[mi][ni], 0, 0, 0);
  }
#pragma unroll
  for (int mi = 0; mi < 4; ++mi)
#pragma unroll
    for (int ni = 0; ni < 4; ++ni) {
      const int n = n0 + wn * 64 + ni * 16 + l15;
#pragma unroll
      for (int r = 0; r < 4; ++r) {
        const int m = m0 + wm * 64 + mi * 16 + g4 * 4 + r;
        float v = acc[mi][ni][r];
        if constexpr (sizeof(OutT) == 2) {
          C[(size_t)m * ldc + n] = (OutT)f2bf(v);
        } else {
          C[(size_t)m * ldc + n] = v;
        }
      }
    }
}

// ---------------- flash attention (local window + global-kv only) ----------------
// Q fragments live in registers (each wave only touches its own 16 q-rows).
// Ks/VTs/Ps are XOR-swizzled at 16B granularity -> conflict-free without padding.
// LDS = 40 KB -> 3 blocks/CU (was 62.5 KB -> 2). Ps is wave-private (rows w*16..+15)
// so no barrier is needed between Ps write and the PV reads.
__global__ __launch_bounds__(256, 3) void attn_kernel(const u16* __restrict__ qkv,
                                                      const u16* __restrict__ vt,
                                                      u16* __restrict__ out) {
  __shared__ __align__(16) u16 Ks[64 * 128];   // swizzled [kv][d]
  __shared__ __align__(16) u16 VTs[128 * 64];  // swizzled [d][kv]
  __shared__ __align__(16) u16 Ps[64 * 64];    // swizzled [q][kv], wave-private rows
  const int q0 = blockIdx.x * 64;
  const int h = blockIdx.y;
  const int tid = threadIdx.x;
  const int w = tid >> 6;
  const int lane = tid & 63;
  const int l15 = lane & 15, g4 = lane >> 4;
  const int l7 = l15 & 7;

  // Q fragments in registers: Q[q0+w*16+l15][h*HD + kk*32 + g4*8 .. +8]
  bf16x8 qf[4];
  {
    const u16* qrow = &qkv[(size_t)(q0 + w * 16 + l15) * NQKV + h * HD + g4 * 8];
#pragma unroll
    for (int kk = 0; kk < 4; ++kk) qf[kk] = *(const bf16x8*)&qrow[kk * 32];
  }

  float m_run = -1e30f, l_run = 0.f;
  f32x4 o[8] = {};

  int lo = q0 - 255;
  int lo_blk = (lo < 0) ? 0 : (lo >> 6);
  int hi_blk = (q0 + 318) >> 6;
  if (hi_blk > 63) hi_blk = 63;
  const int extra = (lo_blk > 0) ? 1 : 0;     // kb=0 pre-pass for global kv cols
  const int nsteps = hi_blk - lo_blk + 1 + extra;

  for (int step = 0; step < nsteps; ++step) {
    const int kb = (extra && step == 0) ? 0 : (lo_blk + step - extra);
    const int kv0 = kb * 64;
    __syncthreads();   // prior iteration's Ks/VTs reads done
    // stage K tile [64 kv][128 d], swizzled
#pragma unroll
    for (int p = 0; p < 4; ++p) {
      int id = p * 256 + tid;
      int r = id >> 4, c8 = id & 15;
      uint4 v = *(const uint4*)&qkv[(size_t)(kv0 + r) * NQKV + 2048 + h * HD + c8 * 8];
      *(uint4*)&Ks[r * 128 + ((c8 ^ (r & 15)) * 8)] = v;
    }
    // stage V^T tile [128 d][64 kv], swizzled
#pragma unroll
    for (int p = 0; p < 4; ++p) {
      int id = p * 256 + tid;
      int r = id >> 3, c8 = id & 7;
      uint4 v = *(const uint4*)&vt[(size_t)h * (HD * SEQ) + (size_t)r * SEQ + kv0 + c8 * 8];
      *(uint4*)&VTs[r * 64 + ((c8 ^ (r & 7)) * 8)] = v;
    }
    __syncthreads();

    // S^T = K @ Q^T : wave w owns q columns [w*16, w*16+16)
    f32x4 st[4] = {};
#pragma unroll
    for (int kk = 0; kk < 4; ++kk) {
#pragma unroll
      for (int t4 = 0; t4 < 4; ++t4) {
        bf16x8 ak = *(const bf16x8*)&Ks[(t4 * 16 + l15) * 128 + (((kk * 4 + g4) ^ l15) * 8)];
        st[t4] = __builtin_amdgcn_mfma_f32_16x16x32_bf16(ak, qf[kk], st[t4], 0, 0, 0);
      }
    }

    // online softmax per q column (q = column index = lane&15 within wave)
    const int q = q0 + w * 16 + l15;
    float pv[4][4];
    float cmax = -1e30f;
#pragma unroll
    for (int t4 = 0; t4 < 4; ++t4)
#pragma unroll
      for (int r = 0; r < 4; ++r) {
        int kv = kv0 + t4 * 16 + g4 * 4 + r;
        int dq = q - kv; if (dq < 0) dq = -dq;
        bool ok = (dq < 256) || (kv < 16);
        float s = ok ? st[t4][r] * SCALE : -1e30f;
        pv[t4][r] = s;
        cmax = fmaxf(cmax, s);
      }
    cmax = fmaxf(cmax, __shfl_xor(cmax, 16, 64));
    cmax = fmaxf(cmax, __shfl_xor(cmax, 32, 64));
    float mnew = fmaxf(m_run, cmax);
    float csum = 0.f;
#pragma unroll
    for (int t4 = 0; t4 < 4; ++t4)
#pragma unroll
      for (int r = 0; r < 4; ++r) {
        float p = __expf(pv[t4][r] - mnew);
        pv[t4][r] = p;
        csum += p;
      }
    csum += __shfl_xor(csum, 16, 64);
    csum += __shfl_xor(csum, 32, 64);
    float alpha = __expf(m_run - mnew);
    m_run = mnew;
    l_run = l_run * alpha + csum;

    // write P (bf16) into wave-private swizzled rows; 4 kv pack to 8B
#pragma unroll
    for (int t4 = 0; t4 < 4; ++t4) {
      u16 pk[4];
#pragma unroll
      for (int r = 0; r < 4; ++r) pk[r] = f2bf(pv[t4][r]);
      int c8 = t4 * 2 + (g4 >> 1);
      *(uint2*)&Ps[(w * 16 + l15) * 64 + ((c8 ^ l7) * 8) + (g4 & 1) * 4] = *(uint2*)pk;
    }

    // rescale O accumulator (O rows are q = g4*4 + r -> fetch that column's alpha)
    float al[4];
#pragma unroll
    for (int r = 0; r < 4; ++r) al[r] = __shfl(alpha, g4 * 4 + r, 64);
#pragma unroll
    for (int nt = 0; nt < 8; ++nt)
#pragma unroll
      for (int r = 0; r < 4; ++r) o[nt][r] *= al[r];

    // O += P @ V : A = wave-private Ps rows, B = VTs (no barrier needed for Ps)
#pragma unroll
    for (int ks = 0; ks < 2; ++ks) {
      bf16x8 ap = *(const bf16x8*)&Ps[(w * 16 + l15) * 64 + (((ks * 4 + g4) ^ l7) * 8)];
#pragma unroll
      for (int nt = 0; nt < 8; ++nt) {
        bf16x8 bv = *(const bf16x8*)&VTs[(nt * 16 + l15) * 64 + (((ks * 4 + g4) ^ l7) * 8)];
        o[nt] = __builtin_amdgcn_mfma_f32_16x16x32_bf16(ap, bv, o[nt], 0, 0, 0);
      }
    }
  }

  // finalize: divide by l (per q row), write bf16; skip global-query rows (<16)
  float lr[4];
#pragma unroll
  for (int r = 0; r < 4; ++r) lr[r] = 1.f / __shfl(l_run, g4 * 4 + r, 64);
#pragma unroll
  for (int nt = 0; nt < 8; ++nt)
#pragma unroll
    for (int r = 0; r < 4; ++r) {
      const int m = q0 + w * 16 + g4 * 4 + r;
      if (m < 16) continue;
      const int n = h * HD + nt * 16 + l15;
      out[(size_t)m * HID + n] = f2bf(o[nt][r] * lr[r]);
    }
}

// ---------------- global queries (q<16): split-KV VALU flash, partials ----------------
__global__ __launch_bounds__(256) void attn_global(const u16* __restrict__ qkv,
                                                   float* __restrict__ Opart,
                                                   float* __restrict__ MLpart) {
  __shared__ __align__(16) u16 Ks[64 * 136];
  __shared__ __align__(16) u16 Vs[64 * 136];
  const int chunk = blockIdx.x, h = blockIdx.y;
  const int t = threadIdx.x;
  const int q = t >> 4, dg = t & 15;

  float qr[8];
  {
    bf16x8 v = *(const bf16x8*)&qkv[(size_t)q * NQKV + h * HD + dg * 8];
#pragma unroll
    for (int j = 0; j < 8; ++j) qr[j] = bf2f((u16)v[j]);
  }
  float m_run = -1e30f, l_run = 0.f, o[8] = {};
  const int kvbase = chunk * (SEQ / GQC);

  for (int st = 0; st < (SEQ / GQC) / 64; ++st) {
    const int kv0 = kvbase + st * 64;
    __syncthreads();
#pragma unroll
    for (int p = 0; p < 4; ++p) {
      int f = (t + p * 256) * 8;
      int r = f >> 7, c = f & 127;
      *(uint4*)&Ks[r * 136 + c] = *(const uint4*)&qkv[(size_t)(kv0 + r) * NQKV + 2048 + h * HD + c];
      *(uint4*)&Vs[r * 136 + c] = *(const uint4*)&qkv[(size_t)(kv0 + r) * NQKV + 4096 + h * HD + c];
    }
    __syncthreads();
    for (int kv = 0; kv < 64; ++kv) {
      bf16x8 kr = *(const bf16x8*)&Ks[kv * 136 + dg * 8];
      float s = 0.f;
#pragma unroll
      for (int j = 0; j < 8; ++j) s += qr[j] * bf2f((u16)kr[j]);
      s += __shfl_xor(s, 1, 64); s += __shfl_xor(s, 2, 64);
      s += __shfl_xor(s, 4, 64); s += __shfl_xor(s, 8, 64);
      s *= SCALE;
      float mnew = fmaxf(m_run, s);
      float alpha = __expf(m_run - mnew);
      float p = __expf(s - mnew);
      m_run = mnew;
      l_run = l_run * alpha + p;
      bf16x8 vr = *(const bf16x8*)&Vs[kv * 136 + dg * 8];
#pragma unroll
      for (int j = 0; j < 8; ++j) o[j] = o[j] * alpha + p * bf2f((u16)vr[j]);
    }
  }
  float* op = &Opart[(((size_t)h * GQC + chunk) * 16 + q) * HD + dg * 8];
#pragma unroll
  for (int j = 0; j < 8; ++j) op[j] = o[j];
  if (dg == 0) {
    float* ml = &MLpart[(((size_t)h * GQC + chunk) * 16 + q) * 2];
    ml[0] = m_run; ml[1] = l_run;
  }
}

// ---------------- combine split-KV partials, write rows 0-15 of AttnO ----------------
__global__ __launch_bounds__(256) void attn_gred(const float* __restrict__ Opart,
                                                 const float* __restrict__ MLpart,
                                                 u16* __restrict__ out) {
  const int h = blockIdx.x;
  const int t = threadIdx.x;
  const int q = t >> 4, dg = t & 15;
  float M = -1e30f;
  for (int c = 0; c < GQC; ++c)
    M = fmaxf(M, MLpart[(((size_t)h * GQC + c) * 16 + q) * 2]);
  float L = 0.f, o[8] = {};
  for (int c = 0; c < GQC; ++c) {
    const float* ml = &MLpart[(((size_t)h * GQC + c) * 16 + q) * 2];
    float e = __expf(ml[0] - M);
    L += e * ml[1];
    const float* op = &Opart[(((size_t)h * GQC + c) * 16 + q) * HD + dg * 8];
#pragma unroll
    for (int j = 0; j < 8; ++j) o[j] += e * op[j];
  }
  float inv = 1.f / L;
  u16 tmp[8];
#pragma unroll
  for (int j = 0; j < 8; ++j) tmp[j] = f2bf(o[j] * inv);
  *(uint4*)&out[(size_t)q * HID + h * HD + dg * 8] = *(uint4*)tmp;
}

extern "C" void kernel_launch(void* const* d_in, const int* in_sizes, int n_in,
                              void* d_out, int out_size, void* d_ws, size_t ws_size,
                              hipStream_t stream) {
  const float* X  = (const float*)d_in[0];
  const float* Wq = (const float*)d_in[1];
  const float* Wk = (const float*)d_in[2];
  const float* Wv = (const float*)d_in[3];
  const float* Wo = (const float*)d_in[4];
  float* out = (float*)d_out;

  char* ws = (char*)d_ws;
  u16* Xbf    = (u16*)(ws);
  u16* Wcat   = (u16*)(ws + (size_t)(16 << 20));
  u16* VT     = (u16*)(ws);                          // alias Xbf
  u16* AttnO  = (u16*)(ws + (size_t)(16 << 20));     // alias Wcat
  float* Opart  = (float*)(ws + (size_t)(32 << 20)); // alias Wcat tail (4 MB)
  float* MLpart = (float*)(ws + (size_t)(36 << 20)); // 64 KB
  u16* QKV    = (u16*)(ws + (size_t)(40 << 20));
  u16* Wot    = (u16*)(ws + (size_t)(88 << 20));

  // 1) X -> bf16
  cvt_f32_bf16<<<dim3(8192), dim3(256), 0, stream>>>(X, Xbf, (SEQ * HID) / 4);
  // 2) weight transposes (fp32 [k][n] -> bf16 [n][k]), fused into one launch
  transpose_w4<<<dim3(32, 32, 4), 256, 0, stream>>>(Wq, Wk, Wv, Wo, Wcat, Wot);
  // 3) fused QKV GEMM: [4096][2048] x [6144][2048]^T -> [4096][6144] bf16
  gemm_bt<u16><<<dim3(48, 32), 256, 0, stream>>>(Xbf, Wcat, QKV, HID, NQKV);
  // 4) global queries: split-KV partials (independent of VT)
  attn_global<<<dim3(GQC, NH), 256, 0, stream>>>(QKV, Opart, MLpart);
  // 5) V -> VT[h][d][s]
  transpose_v<<<dim3(64, 2, 16), 256, 0, stream>>>(QKV, VT);
  // 6) local attention (writes rows 16..4095)
  attn_kernel<<<dim3(64, 16), 256, 0, stream>>>(QKV, VT, AttnO);
  // 7) combine global-query partials (writes rows 0..15)
  attn_gred<<<dim3(NH), 256, 0, stream>>>(Opart, MLpart, AttnO);
  // 8) output projection: [4096][2048] x [2048][2048]^T -> fp32 out
  gemm_bt<float><<<dim3(16, 32), 256, 0, stream>>>(AttnO, Wot, out, HID, HID);
}

// Round 4
// 430.570 us; speedup vs baseline: 1.4501x; 1.0060x over previous
//
#include <hip/hip_runtime.h>
#include <stdint.h>

#define SEQ    4096
#define HID    2048
#define NQKV   6144
#define QKW    4096   // width of the QK row-major buffer (Q | K)
#define NH     16
#define HD     128
#define SCALE  0.08838834764831845f
#define GQC    32     // split-KV chunks for global-query kernel (128 kv each)

typedef unsigned short u16;
typedef __attribute__((ext_vector_type(8))) short bf16x8;
typedef __attribute__((ext_vector_type(4))) float f32x4;
typedef __attribute__((ext_vector_type(16))) float f32x16;

__device__ __forceinline__ u16 f2bf(float f) {
  union { float f; unsigned u; } v; v.f = f;
  unsigned r = v.u + 0x7FFFu + ((v.u >> 16) & 1u);
  return (u16)(r >> 16);
}

__device__ __forceinline__ float bf2f(u16 b) {
  union { unsigned u; float f; } c; c.u = ((unsigned)b) << 16; return c.f;
}

__device__ __forceinline__ void async16(const u16* g, u16* l) {
  __builtin_amdgcn_global_load_lds(
      (const __attribute__((address_space(1))) unsigned int*)g,
      (__attribute__((address_space(3))) unsigned int*)l, 16, 0, 0);
}

// ---------------- fp32 -> bf16 convert (X) ----------------
__global__ __launch_bounds__(256) void cvt_f32_bf16(const float* __restrict__ in,
                                                    u16* __restrict__ out, int n4) {
  int i = blockIdx.x * 256 + threadIdx.x;
  if (i >= n4) return;
  float4 v = ((const float4*)in)[i];
  ushort4 o;
  o.x = f2bf(v.x); o.y = f2bf(v.y); o.z = f2bf(v.z); o.w = f2bf(v.w);
  ((ushort4*)out)[i] = o;
}

// ------ fused weight transposes: z selects {Wq,Wk,Wv}->Wcat, Wo->Wot ------
__global__ __launch_bounds__(256) void transpose_w4(const float* __restrict__ W0,
                                                    const float* __restrict__ W1,
                                                    const float* __restrict__ W2,
                                                    const float* __restrict__ W3,
                                                    u16* __restrict__ Wcat,
                                                    u16* __restrict__ Wot) {
  __shared__ __align__(16) u16 Ts[64 * 72];
  const int n0 = blockIdx.x * 64;
  const int k0 = blockIdx.y * 64;
  const int z = blockIdx.z;
  const float* W = (z == 0) ? W0 : (z == 1) ? W1 : (z == 2) ? W2 : W3;
  u16* Wt = (z < 3) ? (Wcat + (size_t)z * 2048 * 2048) : Wot;
  const int t = threadIdx.x;
#pragma unroll
  for (int p = 0; p < 4; ++p) {
    int f = (t + p * 256) * 4;
    int r = f >> 6, c = f & 63;            // r=k_local, c=n_local
    float4 v = *(const float4*)&W[(size_t)(k0 + r) * 2048 + n0 + c];
    ushort4 o; o.x = f2bf(v.x); o.y = f2bf(v.y); o.z = f2bf(v.z); o.w = f2bf(v.w);
    *(ushort4*)&Ts[r * 72 + c] = o;
  }
  __syncthreads();
#pragma unroll
  for (int p = 0; p < 4; ++p) {
    int g = (t + p * 256) * 4;
    int r = g >> 6, c = g & 63;            // r=n_local, c=k_local
    ushort4 o;
    o.x = Ts[(c + 0) * 72 + r];
    o.y = Ts[(c + 1) * 72 + r];
    o.z = Ts[(c + 2) * 72 + r];
    o.w = Ts[(c + 3) * 72 + r];
    *(ushort4*)&Wt[(size_t)(n0 + r) * 2048 + k0 + c] = o;
  }
}

// ---------------- GEMM: C[m][n] = sum_k A[m][k] * Bt[n][k]  (bf16 in, fp32 acc) ----------------
// 32x32x16 MFMA, 128x128 block, 4 waves each owning 64x64 (2x2 of 32x32 tiles).
// WVT: blocks with n0>=4096 are the V-projection and are written DIRECTLY in
// VT[h][d][s] layout (the C-layout's reg&3 gives 4 consecutive m=s -> 8B packed
// stores), eliminating the separate transpose_v pass.
template <typename OutT, bool WVT>
__global__ __launch_bounds__(256) void gemm_bt(const u16* __restrict__ A,
                                               const u16* __restrict__ B,
                                               OutT* __restrict__ C,
                                               u16* __restrict__ VTout,
                                               int K, int ldc) {
  __shared__ __align__(16) u16 As[128 * 32];
  __shared__ __align__(16) u16 Bs[128 * 32];
  const int m0 = blockIdx.y * 128;
  const int n0 = blockIdx.x * 128;
  const int tid = threadIdx.x;
  const int wid = tid >> 6;
  const int lane = tid & 63;
  const int wm = wid & 1, wn = wid >> 1;
  const int l31 = lane & 31, g2 = lane >> 5;

  const int srow = wid * 32 + (lane >> 2);
  const int scol = (lane & 3) * 8;

  f32x16 acc[2][2] = {};

  const u16* pa0 = &A[(size_t)(m0 + srow) * K + scol];
  const u16* pa1 = &A[(size_t)(m0 + srow + 16) * K + scol];
  const u16* pb0 = &B[(size_t)(n0 + srow) * K + scol];
  const u16* pb1 = &B[(size_t)(n0 + srow + 16) * K + scol];
  u16* la0 = &As[(wid * 32) * 32];
  u16* la1 = &As[(wid * 32 + 16) * 32];
  u16* lb0 = &Bs[(wid * 32) * 32];
  u16* lb1 = &Bs[(wid * 32 + 16) * 32];

  for (int kt = 0; kt < K; kt += 32) {
    __syncthreads();
    async16(pa0 + kt, la0);
    async16(pa1 + kt, la1);
    async16(pb0 + kt, lb0);
    async16(pb1 + kt, lb1);
    __syncthreads();
    bf16x8 af[2][2], bfr[2][2];   // [ks][tile]
#pragma unroll
    for (int ks = 0; ks < 2; ++ks)
#pragma unroll
      for (int i = 0; i < 2; ++i) {
        af[ks][i]  = *(const bf16x8*)&As[(wm * 64 + i * 32 + l31) * 32 + ks * 16 + g2 * 8];
        bfr[ks][i] = *(const bf16x8*)&Bs[(wn * 64 + i * 32 + l31) * 32 + ks * 16 + g2 * 8];
      }
#pragma unroll
    for (int ks = 0; ks < 2; ++ks)
#pragma unroll
      for (int mi = 0; mi < 2; ++mi)
#pragma unroll
        for (int ni = 0; ni < 2; ++ni)
          acc[mi][ni] = __builtin_amdgcn_mfma_f32_32x32x16_bf16(af[ks][mi], bfr[ks][ni],
                                                                acc[mi][ni], 0, 0, 0);
  }

  // C/D layout (m74/m101): col = lane&31, row = (reg&3) + 8*(reg>>2) + 4*(lane>>5)
  if (WVT && n0 >= QKW) {
#pragma unroll
    for (int mi = 0; mi < 2; ++mi)
#pragma unroll
      for (int ni = 0; ni < 2; ++ni) {
        const int nv = n0 - QKW + wn * 64 + ni * 32 + l31;
        const int hh = nv >> 7, dd = nv & 127;
        u16* base = &VTout[((size_t)hh * HD + dd) * SEQ];
#pragma unroll
        for (int rg = 0; rg < 4; ++rg) {
          const int mb = m0 + wm * 64 + mi * 32 + rg * 8 + g2 * 4;
          u16 pk[4];
#pragma unroll
          for (int r = 0; r < 4; ++r) pk[r] = f2bf(acc[mi][ni][rg * 4 + r]);
          *(uint2*)&base[mb] = *(uint2*)pk;
        }
      }
  } else {
#pragma unroll
    for (int mi = 0; mi < 2; ++mi)
#pragma unroll
      for (int ni = 0; ni < 2; ++ni) {
        const int n = n0 + wn * 64 + ni * 32 + l31;
#pragma unroll
        for (int rg = 0; rg < 4; ++rg) {
          const int mb = m0 + wm * 64 + mi * 32 + rg * 8 + g2 * 4;
#pragma unroll
          for (int r = 0; r < 4; ++r) {
            float v = acc[mi][ni][rg * 4 + r];
            if constexpr (sizeof(OutT) == 2) {
              C[(size_t)(mb + r) * ldc + n] = (OutT)f2bf(v);
            } else {
              C[(size_t)(mb + r) * ldc + n] = v;
            }
          }
        }
      }
  }
}

// ---------------- flash attention (local window + global-kv only) ----------------
__global__ __launch_bounds__(256, 3) void attn_kernel(const u16* __restrict__ qk,
                                                      const u16* __restrict__ vt,
                                                      u16* __restrict__ out) {
  __shared__ __align__(16) u16 Ks[64 * 128];   // swizzled [kv][d]
  __shared__ __align__(16) u16 VTs[128 * 64];  // swizzled [d][kv]
  __shared__ __align__(16) u16 Ps[64 * 64];    // swizzled [q][kv], wave-private rows
  const int q0 = blockIdx.x * 64;
  const int h = blockIdx.y;
  const int tid = threadIdx.x;
  const int w = tid >> 6;
  const int lane = tid & 63;
  const int l15 = lane & 15, g4 = lane >> 4;
  const int l7 = l15 & 7;

  // Q fragments in registers
  bf16x8 qf[4];
  {
    const u16* qrow = &qk[(size_t)(q0 + w * 16 + l15) * QKW + h * HD + g4 * 8];
#pragma unroll
    for (int kk = 0; kk < 4; ++kk) qf[kk] = *(const bf16x8*)&qrow[kk * 32];
  }

  float m_run = -1e30f, l_run = 0.f;
  f32x4 o[8] = {};

  int lo = q0 - 255;
  int lo_blk = (lo < 0) ? 0 : (lo >> 6);
  int hi_blk = (q0 + 318) >> 6;
  if (hi_blk > 63) hi_blk = 63;
  const int extra = (lo_blk > 0) ? 1 : 0;     // kb=0 pre-pass for global kv cols
  const int nsteps = hi_blk - lo_blk + 1 + extra;

  for (int step = 0; step < nsteps; ++step) {
    const int kb = (extra && step == 0) ? 0 : (lo_blk + step - extra);
    const int kv0 = kb * 64;
    __syncthreads();
    // stage K tile [64 kv][128 d], swizzled
#pragma unroll
    for (int p = 0; p < 4; ++p) {
      int id = p * 256 + tid;
      int r = id >> 4, c8 = id & 15;
      uint4 v = *(const uint4*)&qk[(size_t)(kv0 + r) * QKW + 2048 + h * HD + c8 * 8];
      *(uint4*)&Ks[r * 128 + ((c8 ^ (r & 15)) * 8)] = v;
    }
    // stage V^T tile [128 d][64 kv], swizzled
#pragma unroll
    for (int p = 0; p < 4; ++p) {
      int id = p * 256 + tid;
      int r = id >> 3, c8 = id & 7;
      uint4 v = *(const uint4*)&vt[(size_t)h * (HD * SEQ) + (size_t)r * SEQ + kv0 + c8 * 8];
      *(uint4*)&VTs[r * 64 + ((c8 ^ (r & 7)) * 8)] = v;
    }
    __syncthreads();

    // S^T = K @ Q^T
    f32x4 st[4] = {};
#pragma unroll
    for (int kk = 0; kk < 4; ++kk) {
#pragma unroll
      for (int t4 = 0; t4 < 4; ++t4) {
        bf16x8 ak = *(const bf16x8*)&Ks[(t4 * 16 + l15) * 128 + (((kk * 4 + g4) ^ l15) * 8)];
        st[t4] = __builtin_amdgcn_mfma_f32_16x16x32_bf16(ak, qf[kk], st[t4], 0, 0, 0);
      }
    }

    // online softmax per q column
    const int q = q0 + w * 16 + l15;
    float pv[4][4];
    float cmax = -1e30f;
#pragma unroll
    for (int t4 = 0; t4 < 4; ++t4)
#pragma unroll
      for (int r = 0; r < 4; ++r) {
        int kv = kv0 + t4 * 16 + g4 * 4 + r;
        int dq = q - kv; if (dq < 0) dq = -dq;
        bool ok = (dq < 256) || (kv < 16);
        float s = ok ? st[t4][r] * SCALE : -1e30f;
        pv[t4][r] = s;
        cmax = fmaxf(cmax, s);
      }
    cmax = fmaxf(cmax, __shfl_xor(cmax, 16, 64));
    cmax = fmaxf(cmax, __shfl_xor(cmax, 32, 64));
    float mnew = fmaxf(m_run, cmax);
    float csum = 0.f;
#pragma unroll
    for (int t4 = 0; t4 < 4; ++t4)
#pragma unroll
      for (int r = 0; r < 4; ++r) {
        float p = __expf(pv[t4][r] - mnew);
        pv[t4][r] = p;
        csum += p;
      }
    csum += __shfl_xor(csum, 16, 64);
    csum += __shfl_xor(csum, 32, 64);
    float alpha = __expf(m_run - mnew);
    m_run = mnew;
    l_run = l_run * alpha + csum;

    // write P (bf16) into wave-private swizzled rows
#pragma unroll
    for (int t4 = 0; t4 < 4; ++t4) {
      u16 pk[4];
#pragma unroll
      for (int r = 0; r < 4; ++r) pk[r] = f2bf(pv[t4][r]);
      int c8 = t4 * 2 + (g4 >> 1);
      *(uint2*)&Ps[(w * 16 + l15) * 64 + ((c8 ^ l7) * 8) + (g4 & 1) * 4] = *(uint2*)pk;
    }

    // rescale O accumulator
    float al[4];
#pragma unroll
    for (int r = 0; r < 4; ++r) al[r] = __shfl(alpha, g4 * 4 + r, 64);
#pragma unroll
    for (int nt = 0; nt < 8; ++nt)
#pragma unroll
      for (int r = 0; r < 4; ++r) o[nt][r] *= al[r];

    // O += P @ V (Ps is wave-private; no barrier needed)
#pragma unroll
    for (int ks = 0; ks < 2; ++ks) {
      bf16x8 ap = *(const bf16x8*)&Ps[(w * 16 + l15) * 64 + (((ks * 4 + g4) ^ l7) * 8)];
#pragma unroll
      for (int nt = 0; nt < 8; ++nt) {
        bf16x8 bv = *(const bf16x8*)&VTs[(nt * 16 + l15) * 64 + (((ks * 4 + g4) ^ l7) * 8)];
        o[nt] = __builtin_amdgcn_mfma_f32_16x16x32_bf16(ap, bv, o[nt], 0, 0, 0);
      }
    }
  }

  // finalize
  float lr[4];
#pragma unroll
  for (int r = 0; r < 4; ++r) lr[r] = 1.f / __shfl(l_run, g4 * 4 + r, 64);
#pragma unroll
  for (int nt = 0; nt < 8; ++nt)
#pragma unroll
    for (int r = 0; r < 4; ++r) {
      const int m = q0 + w * 16 + g4 * 4 + r;
      if (m < 16) continue;
      const int n = h * HD + nt * 16 + l15;
      out[(size_t)m * HID + n] = f2bf(o[nt][r] * lr[r]);
    }
}

// ---------------- global queries (q<16): split-KV VALU flash, partials ----------------
// V is staged from VT[h][d][s] via an LDS transpose (V no longer exists row-major).
__global__ __launch_bounds__(256) void attn_global(const u16* __restrict__ qk,
                                                   const u16* __restrict__ vt,
                                                   float* __restrict__ Opart,
                                                   float* __restrict__ MLpart) {
  __shared__ __align__(16) u16 Ks[64 * 136];
  __shared__ __align__(16) u16 Vs[64 * 136];
  const int chunk = blockIdx.x, h = blockIdx.y;
  const int t = threadIdx.x;
  const int q = t >> 4, dg = t & 15;

  float qr[8];
  {
    bf16x8 v = *(const bf16x8*)&qk[(size_t)q * QKW + h * HD + dg * 8];
#pragma unroll
    for (int j = 0; j < 8; ++j) qr[j] = bf2f((u16)v[j]);
  }
  float m_run = -1e30f, l_run = 0.f, o[8] = {};
  const int kvbase = chunk * (SEQ / GQC);

  for (int st = 0; st < (SEQ / GQC) / 64; ++st) {
    const int kv0 = kvbase + st * 64;
    __syncthreads();
    // K rows
#pragma unroll
    for (int p = 0; p < 4; ++p) {
      int f = (t + p * 256) * 8;
      int r = f >> 7, c = f & 127;
      *(uint4*)&Ks[r * 136 + c] = *(const uint4*)&qk[(size_t)(kv0 + r) * QKW + 2048 + h * HD + c];
    }
    // V via transpose from VT
#pragma unroll
    for (int p = 0; p < 4; ++p) {
      int id = p * 256 + t;
      int d = id >> 3, c8 = id & 7;
      uint4 v = *(const uint4*)&vt[(size_t)h * (HD * SEQ) + (size_t)d * SEQ + kv0 + c8 * 8];
      const u16* pv16 = (const u16*)&v;
#pragma unroll
      for (int j = 0; j < 8; ++j) Vs[(c8 * 8 + j) * 136 + d] = pv16[j];
    }
    __syncthreads();
    for (int kv = 0; kv < 64; ++kv) {
      bf16x8 kr = *(const bf16x8*)&Ks[kv * 136 + dg * 8];
      float s = 0.f;
#pragma unroll
      for (int j = 0; j < 8; ++j) s += qr[j] * bf2f((u16)kr[j]);
      s += __shfl_xor(s, 1, 64); s += __shfl_xor(s, 2, 64);
      s += __shfl_xor(s, 4, 64); s += __shfl_xor(s, 8, 64);
      s *= SCALE;
      float mnew = fmaxf(m_run, s);
      float alpha = __expf(m_run - mnew);
      float p = __expf(s - mnew);
      m_run = mnew;
      l_run = l_run * alpha + p;
      bf16x8 vr = *(const bf16x8*)&Vs[kv * 136 + dg * 8];
#pragma unroll
      for (int j = 0; j < 8; ++j) o[j] = o[j] * alpha + p * bf2f((u16)vr[j]);
    }
  }
  float* op = &Opart[(((size_t)h * GQC + chunk) * 16 + q) * HD + dg * 8];
#pragma unroll
  for (int j = 0; j < 8; ++j) op[j] = o[j];
  if (dg == 0) {
    float* ml = &MLpart[(((size_t)h * GQC + chunk) * 16 + q) * 2];
    ml[0] = m_run; ml[1] = l_run;
  }
}

// ---------------- combine split-KV partials, write rows 0-15 of AttnO ----------------
__global__ __launch_bounds__(256) void attn_gred(const float* __restrict__ Opart,
                                                 const float* __restrict__ MLpart,
                                                 u16* __restrict__ out) {
  const int h = blockIdx.x;
  const int t = threadIdx.x;
  const int q = t >> 4, dg = t & 15;
  float M = -1e30f;
  for (int c = 0; c < GQC; ++c)
    M = fmaxf(M, MLpart[(((size_t)h * GQC + c) * 16 + q) * 2]);
  float L = 0.f, o[8] = {};
  for (int c = 0; c < GQC; ++c) {
    const float* ml = &MLpart[(((size_t)h * GQC + c) * 16 + q) * 2];
    float e = __expf(ml[0] - M);
    L += e * ml[1];
    const float* op = &Opart[(((size_t)h * GQC + c) * 16 + q) * HD + dg * 8];
#pragma unroll
    for (int j = 0; j < 8; ++j) o[j] += e * op[j];
  }
  float inv = 1.f / L;
  u16 tmp[8];
#pragma unroll
  for (int j = 0; j < 8; ++j) tmp[j] = f2bf(o[j] * inv);
  *(uint4*)&out[(size_t)q * HID + h * HD + dg * 8] = *(uint4*)tmp;
}

extern "C" void kernel_launch(void* const* d_in, const int* in_sizes, int n_in,
                              void* d_out, int out_size, void* d_ws, size_t ws_size,
                              hipStream_t stream) {
  const float* X  = (const float*)d_in[0];
  const float* Wq = (const float*)d_in[1];
  const float* Wk = (const float*)d_in[2];
  const float* Wv = (const float*)d_in[3];
  const float* Wo = (const float*)d_in[4];
  float* out = (float*)d_out;

  // workspace layout (96 MiB, lifetime-aliased):
  //  [0,16M):   Xbf   (dead after QKV GEMM)
  //  [16M,40M): Wcat  (dead after QKV GEMM) -> [16M,32M) AttnO, [32M,36M) Opart,
  //                                            [36M,~36.1M) MLpart
  //  [40M,72M): QK row-major [4096][4096] bf16 (Q | K)
  //  [72M,88M): VT[h][d][s] bf16 (written directly by QKV GEMM epilogue)
  //  [88M,96M): Wo^T bf16
  char* ws = (char*)d_ws;
  u16* Xbf    = (u16*)(ws);
  u16* Wcat   = (u16*)(ws + (size_t)(16 << 20));
  u16* AttnO  = (u16*)(ws + (size_t)(16 << 20));     // alias Wcat (post-GEMM)
  float* Opart  = (float*)(ws + (size_t)(32 << 20));
  float* MLpart = (float*)(ws + (size_t)(36 << 20));
  u16* QK     = (u16*)(ws + (size_t)(40 << 20));
  u16* VT     = (u16*)(ws + (size_t)(72 << 20));
  u16* Wot    = (u16*)(ws + (size_t)(88 << 20));

  // 1) X -> bf16
  cvt_f32_bf16<<<dim3(8192), dim3(256), 0, stream>>>(X, Xbf, (SEQ * HID) / 4);
  // 2) weight transposes (fp32 [k][n] -> bf16 [n][k]), one launch
  transpose_w4<<<dim3(32, 32, 4), 256, 0, stream>>>(Wq, Wk, Wv, Wo, Wcat, Wot);
  // 3) fused QKV GEMM: Q,K -> QK row-major; V -> VT transposed
  gemm_bt<u16, true><<<dim3(48, 32), 256, 0, stream>>>(Xbf, Wcat, QK, VT, HID, QKW);
  // 4) global queries: split-KV partials
  attn_global<<<dim3(GQC, NH), 256, 0, stream>>>(QK, VT, Opart, MLpart);
  // 5) local attention (writes rows 16..4095)
  attn_kernel<<<dim3(64, 16), 256, 0, stream>>>(QK, VT, AttnO);
  // 6) combine global-query partials (writes rows 0..15)
  attn_gred<<<dim3(NH), 256, 0, stream>>>(Opart, MLpart, AttnO);
  // 7) output projection -> fp32 out
  gemm_bt<float, false><<<dim3(16, 32), 256, 0, stream>>>(AttnO, Wot, out, nullptr, HID, HID);
}

// Round 5
// 430.247 us; speedup vs baseline: 1.4512x; 1.0008x over previous
//
#include <hip/hip_runtime.h>
#include <stdint.h>

#define SEQ    4096
#define HID    2048
#define NQKV   6144
#define QKW    4096   // width of the QK row-major buffer (Q | K)
#define NH     16
#define HD     128
#define SCALE  0.08838834764831845f
#define GQC    32     // split-KV chunks for global-query kernel (128 kv each)

typedef unsigned short u16;
typedef __attribute__((ext_vector_type(8))) short bf16x8;
typedef __attribute__((ext_vector_type(4))) float f32x4;
typedef __attribute__((ext_vector_type(16))) float f32x16;

__device__ __forceinline__ u16 f2bf(float f) {
  union { float f; unsigned u; } v; v.f = f;
  unsigned r = v.u + 0x7FFFu + ((v.u >> 16) & 1u);
  return (u16)(r >> 16);
}

__device__ __forceinline__ float bf2f(u16 b) {
  union { unsigned u; float f; } c; c.u = ((unsigned)b) << 16; return c.f;
}

__device__ __forceinline__ void async16(const u16* g, u16* l) {
  __builtin_amdgcn_global_load_lds(
      (const __attribute__((address_space(1))) unsigned int*)g,
      (__attribute__((address_space(3))) unsigned int*)l, 16, 0, 0);
}

// ---------------- fp32 -> bf16 convert (X) ----------------
__global__ __launch_bounds__(256) void cvt_f32_bf16(const float* __restrict__ in,
                                                    u16* __restrict__ out, int n4) {
  int i = blockIdx.x * 256 + threadIdx.x;
  if (i >= n4) return;
  float4 v = ((const float4*)in)[i];
  ushort4 o;
  o.x = f2bf(v.x); o.y = f2bf(v.y); o.z = f2bf(v.z); o.w = f2bf(v.w);
  ((ushort4*)out)[i] = o;
}

// ------ fused weight transposes: z selects {Wq,Wk,Wv}->Wcat, Wo->Wot ------
__global__ __launch_bounds__(256) void transpose_w4(const float* __restrict__ W0,
                                                    const float* __restrict__ W1,
                                                    const float* __restrict__ W2,
                                                    const float* __restrict__ W3,
                                                    u16* __restrict__ Wcat,
                                                    u16* __restrict__ Wot) {
  __shared__ __align__(16) u16 Ts[64 * 72];
  const int n0 = blockIdx.x * 64;
  const int k0 = blockIdx.y * 64;
  const int z = blockIdx.z;
  const float* W = (z == 0) ? W0 : (z == 1) ? W1 : (z == 2) ? W2 : W3;
  u16* Wt = (z < 3) ? (Wcat + (size_t)z * 2048 * 2048) : Wot;
  const int t = threadIdx.x;
#pragma unroll
  for (int p = 0; p < 4; ++p) {
    int f = (t + p * 256) * 4;
    int r = f >> 6, c = f & 63;            // r=k_local, c=n_local
    float4 v = *(const float4*)&W[(size_t)(k0 + r) * 2048 + n0 + c];
    ushort4 o; o.x = f2bf(v.x); o.y = f2bf(v.y); o.z = f2bf(v.z); o.w = f2bf(v.w);
    *(ushort4*)&Ts[r * 72 + c] = o;
  }
  __syncthreads();
#pragma unroll
  for (int p = 0; p < 4; ++p) {
    int g = (t + p * 256) * 4;
    int r = g >> 6, c = g & 63;            // r=n_local, c=k_local
    ushort4 o;
    o.x = Ts[(c + 0) * 72 + r];
    o.y = Ts[(c + 1) * 72 + r];
    o.z = Ts[(c + 2) * 72 + r];
    o.w = Ts[(c + 3) * 72 + r];
    *(ushort4*)&Wt[(size_t)(n0 + r) * 2048 + k0 + c] = o;
  }
}

// ---------------- GEMM: C[m][n] = sum_k A[m][k] * Bt[n][k]  (bf16 in, fp32 acc) ----------------
// 32x32x16 MFMA, 128x128 block, 4 waves each owning 64x64 (2x2 of 32x32 tiles).
// LDS tiles are XOR-swizzled at 16B granularity: chunk c of row r is stored at
// slot c^(r&3). global_load_lds pins LDS dest = base+lane*16, so the swizzle is
// implemented by permuting each lane's global SOURCE chunk. This spreads the
// 32-row fragment reads across all 8 bank-slots (8 lanes/slot = LDS BW floor);
// the unswizzled layout hit only half the slots (16 lanes/slot, 2x cycles).
template <typename OutT, bool WVT>
__global__ __launch_bounds__(256) void gemm_bt(const u16* __restrict__ A,
                                               const u16* __restrict__ B,
                                               OutT* __restrict__ C,
                                               u16* __restrict__ VTout,
                                               int K, int ldc) {
  __shared__ __align__(16) u16 As[128 * 32];
  __shared__ __align__(16) u16 Bs[128 * 32];
  const int m0 = blockIdx.y * 128;
  const int n0 = blockIdx.x * 128;
  const int tid = threadIdx.x;
  const int wid = tid >> 6;
  const int lane = tid & 63;
  const int wm = wid & 1, wn = wid >> 1;
  const int l31 = lane & 31, g2 = lane >> 5;

  const int srow = wid * 32 + (lane >> 2);
  // swizzled source chunk: lane's LDS slot is (lane&3); fetch chunk (lane&3)^(row&3)
  const int scol = (((lane & 3) ^ ((lane >> 2) & 3)) * 8);

  f32x16 acc[2][2] = {};

  const u16* pa0 = &A[(size_t)(m0 + srow) * K + scol];
  const u16* pa1 = &A[(size_t)(m0 + srow + 16) * K + scol];
  const u16* pb0 = &B[(size_t)(n0 + srow) * K + scol];
  const u16* pb1 = &B[(size_t)(n0 + srow + 16) * K + scol];
  u16* la0 = &As[(wid * 32) * 32];
  u16* la1 = &As[(wid * 32 + 16) * 32];
  u16* lb0 = &Bs[(wid * 32) * 32];
  u16* lb1 = &Bs[(wid * 32 + 16) * 32];

  for (int kt = 0; kt < K; kt += 32) {
    __syncthreads();
    async16(pa0 + kt, la0);
    async16(pa1 + kt, la1);
    async16(pb0 + kt, lb0);
    async16(pb1 + kt, lb1);
    __syncthreads();
    bf16x8 af[2][2], bfr[2][2];   // [ks][tile]
#pragma unroll
    for (int ks = 0; ks < 2; ++ks)
#pragma unroll
      for (int i = 0; i < 2; ++i) {
        const int slot = ((ks * 2 + g2) ^ (l31 & 3)) * 8;   // de-swizzle
        af[ks][i]  = *(const bf16x8*)&As[(wm * 64 + i * 32 + l31) * 32 + slot];
        bfr[ks][i] = *(const bf16x8*)&Bs[(wn * 64 + i * 32 + l31) * 32 + slot];
      }
#pragma unroll
    for (int ks = 0; ks < 2; ++ks)
#pragma unroll
      for (int mi = 0; mi < 2; ++mi)
#pragma unroll
        for (int ni = 0; ni < 2; ++ni)
          acc[mi][ni] = __builtin_amdgcn_mfma_f32_32x32x16_bf16(af[ks][mi], bfr[ks][ni],
                                                                acc[mi][ni], 0, 0, 0);
  }

  // C/D layout (m74/m101): col = lane&31, row = (reg&3) + 8*(reg>>2) + 4*(lane>>5)
  if (WVT && n0 >= QKW) {
#pragma unroll
    for (int mi = 0; mi < 2; ++mi)
#pragma unroll
      for (int ni = 0; ni < 2; ++ni) {
        const int nv = n0 - QKW + wn * 64 + ni * 32 + l31;
        const int hh = nv >> 7, dd = nv & 127;
        u16* base = &VTout[((size_t)hh * HD + dd) * SEQ];
#pragma unroll
        for (int rg = 0; rg < 4; ++rg) {
          const int mb = m0 + wm * 64 + mi * 32 + rg * 8 + g2 * 4;
          u16 pk[4];
#pragma unroll
          for (int r = 0; r < 4; ++r) pk[r] = f2bf(acc[mi][ni][rg * 4 + r]);
          *(uint2*)&base[mb] = *(uint2*)pk;
        }
      }
  } else {
#pragma unroll
    for (int mi = 0; mi < 2; ++mi)
#pragma unroll
      for (int ni = 0; ni < 2; ++ni) {
        const int n = n0 + wn * 64 + ni * 32 + l31;
#pragma unroll
        for (int rg = 0; rg < 4; ++rg) {
          const int mb = m0 + wm * 64 + mi * 32 + rg * 8 + g2 * 4;
#pragma unroll
          for (int r = 0; r < 4; ++r) {
            float v = acc[mi][ni][rg * 4 + r];
            if constexpr (sizeof(OutT) == 2) {
              C[(size_t)(mb + r) * ldc + n] = (OutT)f2bf(v);
            } else {
              C[(size_t)(mb + r) * ldc + n] = v;
            }
          }
        }
      }
  }
}

// ---------------- flash attention (local window + global-kv only) ----------------
__global__ __launch_bounds__(256, 3) void attn_kernel(const u16* __restrict__ qk,
                                                      const u16* __restrict__ vt,
                                                      u16* __restrict__ out) {
  __shared__ __align__(16) u16 Ks[64 * 128];   // swizzled [kv][d]
  __shared__ __align__(16) u16 VTs[128 * 64];  // swizzled [d][kv]
  __shared__ __align__(16) u16 Ps[64 * 64];    // swizzled [q][kv], wave-private rows
  const int q0 = blockIdx.x * 64;
  const int h = blockIdx.y;
  const int tid = threadIdx.x;
  const int w = tid >> 6;
  const int lane = tid & 63;
  const int l15 = lane & 15, g4 = lane >> 4;
  const int l7 = l15 & 7;

  // Q fragments in registers
  bf16x8 qf[4];
  {
    const u16* qrow = &qk[(size_t)(q0 + w * 16 + l15) * QKW + h * HD + g4 * 8];
#pragma unroll
    for (int kk = 0; kk < 4; ++kk) qf[kk] = *(const bf16x8*)&qrow[kk * 32];
  }

  float m_run = -1e30f, l_run = 0.f;
  f32x4 o[8] = {};

  int lo = q0 - 255;
  int lo_blk = (lo < 0) ? 0 : (lo >> 6);
  int hi_blk = (q0 + 318) >> 6;
  if (hi_blk > 63) hi_blk = 63;
  const int extra = (lo_blk > 0) ? 1 : 0;     // kb=0 pre-pass for global kv cols
  const int nsteps = hi_blk - lo_blk + 1 + extra;

  for (int step = 0; step < nsteps; ++step) {
    const int kb = (extra && step == 0) ? 0 : (lo_blk + step - extra);
    const int kv0 = kb * 64;
    __syncthreads();
    // stage K tile [64 kv][128 d], swizzled
#pragma unroll
    for (int p = 0; p < 4; ++p) {
      int id = p * 256 + tid;
      int r = id >> 4, c8 = id & 15;
      uint4 v = *(const uint4*)&qk[(size_t)(kv0 + r) * QKW + 2048 + h * HD + c8 * 8];
      *(uint4*)&Ks[r * 128 + ((c8 ^ (r & 15)) * 8)] = v;
    }
    // stage V^T tile [128 d][64 kv], swizzled
#pragma unroll
    for (int p = 0; p < 4; ++p) {
      int id = p * 256 + tid;
      int r = id >> 3, c8 = id & 7;
      uint4 v = *(const uint4*)&vt[(size_t)h * (HD * SEQ) + (size_t)r * SEQ + kv0 + c8 * 8];
      *(uint4*)&VTs[r * 64 + ((c8 ^ (r & 7)) * 8)] = v;
    }
    __syncthreads();

    // S^T = K @ Q^T
    f32x4 st[4] = {};
#pragma unroll
    for (int kk = 0; kk < 4; ++kk) {
#pragma unroll
      for (int t4 = 0; t4 < 4; ++t4) {
        bf16x8 ak = *(const bf16x8*)&Ks[(t4 * 16 + l15) * 128 + (((kk * 4 + g4) ^ l15) * 8)];
        st[t4] = __builtin_amdgcn_mfma_f32_16x16x32_bf16(ak, qf[kk], st[t4], 0, 0, 0);
      }
    }

    // online softmax per q column
    const int q = q0 + w * 16 + l15;
    float pv[4][4];
    float cmax = -1e30f;
#pragma unroll
    for (int t4 = 0; t4 < 4; ++t4)
#pragma unroll
      for (int r = 0; r < 4; ++r) {
        int kv = kv0 + t4 * 16 + g4 * 4 + r;
        int dq = q - kv; if (dq < 0) dq = -dq;
        bool ok = (dq < 256) || (kv < 16);
        float s = ok ? st[t4][r] * SCALE : -1e30f;
        pv[t4][r] = s;
        cmax = fmaxf(cmax, s);
      }
    cmax = fmaxf(cmax, __shfl_xor(cmax, 16, 64));
    cmax = fmaxf(cmax, __shfl_xor(cmax, 32, 64));
    float mnew = fmaxf(m_run, cmax);
    float csum = 0.f;
#pragma unroll
    for (int t4 = 0; t4 < 4; ++t4)
#pragma unroll
      for (int r = 0; r < 4; ++r) {
        float p = __expf(pv[t4][r] - mnew);
        pv[t4][r] = p;
        csum += p;
      }
    csum += __shfl_xor(csum, 16, 64);
    csum += __shfl_xor(csum, 32, 64);
    float alpha = __expf(m_run - mnew);
    m_run = mnew;
    l_run = l_run * alpha + csum;

    // write P (bf16) into wave-private swizzled rows
#pragma unroll
    for (int t4 = 0; t4 < 4; ++t4) {
      u16 pk[4];
#pragma unroll
      for (int r = 0; r < 4; ++r) pk[r] = f2bf(pv[t4][r]);
      int c8 = t4 * 2 + (g4 >> 1);
      *(uint2*)&Ps[(w * 16 + l15) * 64 + ((c8 ^ l7) * 8) + (g4 & 1) * 4] = *(uint2*)pk;
    }

    // rescale O accumulator
    float al[4];
#pragma unroll
    for (int r = 0; r < 4; ++r) al[r] = __shfl(alpha, g4 * 4 + r, 64);
#pragma unroll
    for (int nt = 0; nt < 8; ++nt)
#pragma unroll
      for (int r = 0; r < 4; ++r) o[nt][r] *= al[r];

    // O += P @ V (Ps is wave-private; no barrier needed)
#pragma unroll
    for (int ks = 0; ks < 2; ++ks) {
      bf16x8 ap = *(const bf16x8*)&Ps[(w * 16 + l15) * 64 + (((ks * 4 + g4) ^ l7) * 8)];
#pragma unroll
      for (int nt = 0; nt < 8; ++nt) {
        bf16x8 bv = *(const bf16x8*)&VTs[(nt * 16 + l15) * 64 + (((ks * 4 + g4) ^ l7) * 8)];
        o[nt] = __builtin_amdgcn_mfma_f32_16x16x32_bf16(ap, bv, o[nt], 0, 0, 0);
      }
    }
  }

  // finalize
  float lr[4];
#pragma unroll
  for (int r = 0; r < 4; ++r) lr[r] = 1.f / __shfl(l_run, g4 * 4 + r, 64);
#pragma unroll
  for (int nt = 0; nt < 8; ++nt)
#pragma unroll
    for (int r = 0; r < 4; ++r) {
      const int m = q0 + w * 16 + g4 * 4 + r;
      if (m < 16) continue;
      const int n = h * HD + nt * 16 + l15;
      out[(size_t)m * HID + n] = f2bf(o[nt][r] * lr[r]);
    }
}

// ---------------- global queries (q<16): split-KV VALU flash, partials ----------------
__global__ __launch_bounds__(256) void attn_global(const u16* __restrict__ qk,
                                                   const u16* __restrict__ vt,
                                                   float* __restrict__ Opart,
                                                   float* __restrict__ MLpart) {
  __shared__ __align__(16) u16 Ks[64 * 136];
  __shared__ __align__(16) u16 Vs[64 * 136];
  const int chunk = blockIdx.x, h = blockIdx.y;
  const int t = threadIdx.x;
  const int q = t >> 4, dg = t & 15;

  float qr[8];
  {
    bf16x8 v = *(const bf16x8*)&qk[(size_t)q * QKW + h * HD + dg * 8];
#pragma unroll
    for (int j = 0; j < 8; ++j) qr[j] = bf2f((u16)v[j]);
  }
  float m_run = -1e30f, l_run = 0.f, o[8] = {};
  const int kvbase = chunk * (SEQ / GQC);

  for (int st = 0; st < (SEQ / GQC) / 64; ++st) {
    const int kv0 = kvbase + st * 64;
    __syncthreads();
    // K rows
#pragma unroll
    for (int p = 0; p < 4; ++p) {
      int f = (t + p * 256) * 8;
      int r = f >> 7, c = f & 127;
      *(uint4*)&Ks[r * 136 + c] = *(const uint4*)&qk[(size_t)(kv0 + r) * QKW + 2048 + h * HD + c];
    }
    // V via transpose from VT
#pragma unroll
    for (int p = 0; p < 4; ++p) {
      int id = p * 256 + t;
      int d = id >> 3, c8 = id & 7;
      uint4 v = *(const uint4*)&vt[(size_t)h * (HD * SEQ) + (size_t)d * SEQ + kv0 + c8 * 8];
      const u16* pv16 = (const u16*)&v;
#pragma unroll
      for (int j = 0; j < 8; ++j) Vs[(c8 * 8 + j) * 136 + d] = pv16[j];
    }
    __syncthreads();
    for (int kv = 0; kv < 64; ++kv) {
      bf16x8 kr = *(const bf16x8*)&Ks[kv * 136 + dg * 8];
      float s = 0.f;
#pragma unroll
      for (int j = 0; j < 8; ++j) s += qr[j] * bf2f((u16)kr[j]);
      s += __shfl_xor(s, 1, 64); s += __shfl_xor(s, 2, 64);
      s += __shfl_xor(s, 4, 64); s += __shfl_xor(s, 8, 64);
      s *= SCALE;
      float mnew = fmaxf(m_run, s);
      float alpha = __expf(m_run - mnew);
      float p = __expf(s - mnew);
      m_run = mnew;
      l_run = l_run * alpha + p;
      bf16x8 vr = *(const bf16x8*)&Vs[kv * 136 + dg * 8];
#pragma unroll
      for (int j = 0; j < 8; ++j) o[j] = o[j] * alpha + p * bf2f((u16)vr[j]);
    }
  }
  float* op = &Opart[(((size_t)h * GQC + chunk) * 16 + q) * HD + dg * 8];
#pragma unroll
  for (int j = 0; j < 8; ++j) op[j] = o[j];
  if (dg == 0) {
    float* ml = &MLpart[(((size_t)h * GQC + chunk) * 16 + q) * 2];
    ml[0] = m_run; ml[1] = l_run;
  }
}

// ---------------- combine split-KV partials, write rows 0-15 of AttnO ----------------
__global__ __launch_bounds__(256) void attn_gred(const float* __restrict__ Opart,
                                                 const float* __restrict__ MLpart,
                                                 u16* __restrict__ out) {
  const int h = blockIdx.x;
  const int t = threadIdx.x;
  const int q = t >> 4, dg = t & 15;
  float M = -1e30f;
  for (int c = 0; c < GQC; ++c)
    M = fmaxf(M, MLpart[(((size_t)h * GQC + c) * 16 + q) * 2]);
  float L = 0.f, o[8] = {};
  for (int c = 0; c < GQC; ++c) {
    const float* ml = &MLpart[(((size_t)h * GQC + c) * 16 + q) * 2];
    float e = __expf(ml[0] - M);
    L += e * ml[1];
    const float* op = &Opart[(((size_t)h * GQC + c) * 16 + q) * HD + dg * 8];
#pragma unroll
    for (int j = 0; j < 8; ++j) o[j] += e * op[j];
  }
  float inv = 1.f / L;
  u16 tmp[8];
#pragma unroll
  for (int j = 0; j < 8; ++j) tmp[j] = f2bf(o[j] * inv);
  *(uint4*)&out[(size_t)q * HID + h * HD + dg * 8] = *(uint4*)tmp;
}

extern "C" void kernel_launch(void* const* d_in, const int* in_sizes, int n_in,
                              void* d_out, int out_size, void* d_ws, size_t ws_size,
                              hipStream_t stream) {
  const float* X  = (const float*)d_in[0];
  const float* Wq = (const float*)d_in[1];
  const float* Wk = (const float*)d_in[2];
  const float* Wv = (const float*)d_in[3];
  const float* Wo = (const float*)d_in[4];
  float* out = (float*)d_out;

  // workspace layout (96 MiB, lifetime-aliased):
  //  [0,16M):   Xbf   (dead after QKV GEMM)
  //  [16M,40M): Wcat  (dead after QKV GEMM) -> [16M,32M) AttnO, [32M,36M) Opart,
  //                                            [36M,~36.1M) MLpart
  //  [40M,72M): QK row-major [4096][4096] bf16 (Q | K)
  //  [72M,88M): VT[h][d][s] bf16 (written directly by QKV GEMM epilogue)
  //  [88M,96M): Wo^T bf16
  char* ws = (char*)d_ws;
  u16* Xbf    = (u16*)(ws);
  u16* Wcat   = (u16*)(ws + (size_t)(16 << 20));
  u16* AttnO  = (u16*)(ws + (size_t)(16 << 20));     // alias Wcat (post-GEMM)
  float* Opart  = (float*)(ws + (size_t)(32 << 20));
  float* MLpart = (float*)(ws + (size_t)(36 << 20));
  u16* QK     = (u16*)(ws + (size_t)(40 << 20));
  u16* VT     = (u16*)(ws + (size_t)(72 << 20));
  u16* Wot    = (u16*)(ws + (size_t)(88 << 20));

  // 1) X -> bf16
  cvt_f32_bf16<<<dim3(8192), dim3(256), 0, stream>>>(X, Xbf, (SEQ * HID) / 4);
  // 2) weight transposes (fp32 [k][n] -> bf16 [n][k]), one launch
  transpose_w4<<<dim3(32, 32, 4), 256, 0, stream>>>(Wq, Wk, Wv, Wo, Wcat, Wot);
  // 3) fused QKV GEMM: Q,K -> QK row-major; V -> VT transposed
  gemm_bt<u16, true><<<dim3(48, 32), 256, 0, stream>>>(Xbf, Wcat, QK, VT, HID, QKW);
  // 4) global queries: split-KV partials
  attn_global<<<dim3(GQC, NH), 256, 0, stream>>>(QK, VT, Opart, MLpart);
  // 5) local attention (writes rows 16..4095)
  attn_kernel<<<dim3(64, 16), 256, 0, stream>>>(QK, VT, AttnO);
  // 6) combine global-query partials (writes rows 0..15)
  attn_gred<<<dim3(NH), 256, 0, stream>>>(Opart, MLpart, AttnO);
  // 7) output projection -> fp32 out
  gemm_bt<float, false><<<dim3(16, 32), 256, 0, stream>>>(AttnO, Wot, out, nullptr, HID, HID);
}